// Round 16
// baseline (46.545 us; speedup 1.0000x reference)
//
#include <hip/hip_runtime.h>
#include <math.h>

// LAPACK >= 3.10 slartg convention (c >= 0). Flip to 0 to emulate <= 3.9.
#define NEW_SLARTG 1

typedef __attribute__((ext_vector_type(8))) short bf16x8;
typedef __attribute__((ext_vector_type(4))) float f32x4;

// =============================================================================
// LAPACK sgesdd emulation for 3x3 (f32), faithful sign conventions.
// FULLY SCALARIZED (round 10); 16 blocks x 1 SVD (round 12) — unchanged.
// =============================================================================

__device__ __forceinline__ void slartg_f(float f, float g, float& c, float& s, float& r) {
#if NEW_SLARTG
  if (g == 0.0f) { c = 1.0f; s = 0.0f; r = f; }
  else if (f == 0.0f) { c = 0.0f; s = copysignf(1.0f, g); r = fabsf(g); }
  else {
    float d = sqrtf(f*f + g*g);
    c = fabsf(f) / d;
    r = copysignf(d, f);
    s = g / r;
  }
#else
  if (g == 0.0f) { c = 1.0f; s = 0.0f; r = f; }
  else if (f == 0.0f) { c = 0.0f; s = 1.0f; r = g; }
  else {
    float d = sqrtf(f*f + g*g);
    c = f / d; s = g / d; r = d;
    if (fabsf(f) > fabsf(g) && c < 0.0f) { c = -c; s = -s; r = -r; }
  }
#endif
}

__device__ __forceinline__ void slas2_f(float f, float g, float h, float& ssmin, float& ssmax) {
  float fa = fabsf(f), ga = fabsf(g), ha = fabsf(h);
  float fhmn = fminf(fa, ha), fhmx = fmaxf(fa, ha);
  if (fhmn == 0.0f) {
    ssmin = 0.0f;
    if (fhmx == 0.0f) ssmax = ga;
    else {
      float mn = fminf(fhmx, ga), mx = fmaxf(fhmx, ga);
      float qq = mn / mx;
      ssmax = mx * sqrtf(1.0f + qq*qq);
    }
  } else {
    if (ga < fhmx) {
      float as_ = 1.0f + fhmn/fhmx;
      float at_ = (fhmx - fhmn)/fhmx;
      float au_ = ga/fhmx; au_ = au_*au_;
      float c = 2.0f/(sqrtf(as_*as_ + au_) + sqrtf(at_*at_ + au_));
      ssmin = fhmn*c;
      ssmax = fhmx/c;
    } else {
      float au_ = fhmx/ga;
      if (au_ == 0.0f) {
        ssmin = (fhmn*fhmx)/ga;
        ssmax = ga;
      } else {
        float as_ = 1.0f + fhmn/fhmx;
        float at_ = (fhmx - fhmn)/fhmx;
        float t1 = as_*au_, t2 = at_*au_;
        float c = 1.0f/(sqrtf(1.0f + t1*t1) + sqrtf(1.0f + t2*t2));
        ssmin = (fhmn*c)*au_;
        ssmin = ssmin + ssmin;
        ssmax = ga/(c + c);
      }
    }
  }
}

__device__ __forceinline__ void slasv2_f(float f, float g, float h,
                         float& ssmin, float& ssmax,
                         float& snr, float& csr, float& snl, float& csl) {
  const float eps = 5.9604645e-08f;
  float ft = f, fa = fabsf(f), ht = h, ha = fabsf(h);
  int pmax = 1;
  bool swap_ = (ha > fa);
  if (swap_) {
    pmax = 3;
    float tq = ft; ft = ht; ht = tq;
    tq = fa; fa = ha; ha = tq;
  }
  float gt = g, ga = fabsf(g);
  float clt = 0.f, crt = 0.f, slt = 0.f, srt = 0.f;
  if (ga == 0.0f) {
    ssmin = ha; ssmax = fa;
    clt = 1.0f; crt = 1.0f; slt = 0.0f; srt = 0.0f;
  } else {
    bool gasmal = true;
    if (ga > fa) {
      pmax = 2;
      if ((fa/ga) < eps) {
        gasmal = false;
        ssmax = ga;
        ssmin = (ha > 1.0f) ? (fa/(ga/ha)) : ((fa/ga)*ha);
        clt = 1.0f; slt = ht/gt; srt = 1.0f; crt = ft/gt;
      }
    }
    if (gasmal) {
      float dd = fa - ha;
      float l = (dd == fa) ? 1.0f : (dd/fa);
      float mr = gt/ft;
      float t = 2.0f - l;
      float mm2 = mr*mr, tt = t*t;
      float s_ = sqrtf(tt + mm2);
      float r_ = (l == 0.0f) ? fabsf(mr) : sqrtf(l*l + mm2);
      float a_ = 0.5f*(s_ + r_);
      ssmin = ha/a_;
      ssmax = fa*a_;
      if (mm2 == 0.0f) {
        if (l == 0.0f) t = copysignf(2.0f, ft)*copysignf(1.0f, gt);
        else t = gt/copysignf(dd, ft) + mr/t;
      } else {
        t = (mr/(s_ + t) + mr/(r_ + l))*(1.0f + a_);
      }
      float l2 = sqrtf(t*t + 4.0f);
      crt = 2.0f/l2;
      srt = t/l2;
      clt = (crt + srt*mr)/a_;
      slt = (ht/ft)*srt/a_;
    }
  }
  if (swap_) { csl = srt; snl = crt; csr = slt; snr = clt; }
  else       { csl = clt; snl = slt; csr = crt; snr = srt; }
  float tsign = 0.f;
  if (pmax == 1) tsign = copysignf(1.0f, csr)*copysignf(1.0f, csl)*copysignf(1.0f, f);
  if (pmax == 2) tsign = copysignf(1.0f, snr)*copysignf(1.0f, csl)*copysignf(1.0f, g);
  if (pmax == 3) tsign = copysignf(1.0f, snr)*copysignf(1.0f, snl)*copysignf(1.0f, h);
  ssmax = copysignf(ssmax, tsign);
  ssmin = copysignf(ssmin, tsign*copysignf(1.0f, f)*copysignf(1.0f, h));
}

// rotation / swap helpers with COMPILE-TIME indices (template params)
template<int R1, int R2>
__device__ __forceinline__ void rotr(float mt[3][3], float c, float s) {
#pragma unroll
  for (int k = 0; k < 3; ++k) {
    float x = mt[R1][k], y = mt[R2][k];
    mt[R1][k] = c*x + s*y;
    mt[R2][k] = c*y - s*x;
  }
}
template<int C1, int C2>
__device__ __forceinline__ void rotc(float mt[3][3], float c, float s) {
#pragma unroll
  for (int k = 0; k < 3; ++k) {
    float x = mt[k][C1], y = mt[k][C2];
    mt[k][C1] = c*x + s*y;
    mt[k][C2] = c*y - s*x;
  }
}
template<int R1, int R2>
__device__ __forceinline__ void swaprow(float mt[3][3]) {
#pragma unroll
  for (int k = 0; k < 3; ++k) { float t = mt[R1][k]; mt[R1][k] = mt[R2][k]; mt[R2][k] = t; }
}
template<int C1, int C2>
__device__ __forceinline__ void swapcol(float mt[3][3]) {
#pragma unroll
  for (int k = 0; k < 3; ++k) { float t = mt[k][C1]; mt[k][C1] = mt[k][C2]; mt[k][C2] = t; }
}

// SBDSQR specialized for n=3 upper bidiagonal, all-register state.
__device__ __forceinline__ void sbdsqr3_reg(float& d1, float& d2, float& d3,
                                            float& e1, float& e2,
                                            float u[3][3], float vt[3][3]) {
  const float eps  = 5.9604645e-08f;
  const float unfl = 1.17549435e-38f;
  const float tol  = 10.0f*eps;

  float sminoa = fabsf(d1);
  if (sminoa != 0.0f) {
    float mu = sminoa;
    mu = fabsf(d2)*(mu/(mu + fabsf(e1)));
    sminoa = fminf(sminoa, mu);
    if (sminoa != 0.0f) {
      mu = fabsf(d3)*(mu/(mu + fabsf(e2)));
      sminoa = fminf(sminoa, mu);
    }
  }
  sminoa = sminoa / sqrtf(3.0f);
  float thresh = fmaxf(tol*sminoa, 54.0f*unfl);

  int m = 3, oldll = -1, oldm = -1, idir = 0;
  int guard = 0;
  while (m > 1 && ++guard < 200) {
    if (m == 2) {
      if (fabsf(e1) <= thresh) { e1 = 0.0f; m = 1; continue; }
      float sigmn, sigmx, sinr, cosr, sinl, cosl;
      slasv2_f(d1, e1, d2, sigmn, sigmx, sinr, cosr, sinl, cosl);
      d1 = sigmx; d2 = sigmn; e1 = 0.0f;
      rotr<0,1>(vt, cosr, sinr);
      rotc<0,1>(u,  cosl, sinl);
      m = 0; continue;
    }
    // ---- m == 3 ----
    float smax = fabsf(d3);
    if (fabsf(e2) <= thresh) { e2 = 0.0f; m = 2; continue; }
    smax = fmaxf(smax, fmaxf(fabsf(d2), fabsf(e2)));
    if (fabsf(e1) <= thresh) {
      e1 = 0.0f;
      float sigmn, sigmx, sinr, cosr, sinl, cosl;
      slasv2_f(d2, e2, d3, sigmn, sigmx, sinr, cosr, sinl, cosl);
      d2 = sigmx; d3 = sigmn; e2 = 0.0f;
      rotr<1,2>(vt, cosr, sinr);
      rotc<1,2>(u,  cosl, sinl);
      m = 1; continue;
    }
    smax = fmaxf(smax, fmaxf(fabsf(d1), fabsf(e1)));

    if (1 > oldm || 3 < oldll)
      idir = (fabsf(d1) >= fabsf(d3)) ? 1 : 2;

    float sminl = 0.0f;
    if (idir == 1) {
      if (fabsf(e2) <= tol*fabsf(d3)) { e2 = 0.0f; continue; }
      float mu = fabsf(d1); sminl = mu;
      if (fabsf(e1) <= tol*mu) { e1 = 0.0f; continue; }
      mu = fabsf(d2)*(mu/(mu + fabsf(e1))); sminl = fminf(sminl, mu);
      if (fabsf(e2) <= tol*mu) { e2 = 0.0f; continue; }
      mu = fabsf(d3)*(mu/(mu + fabsf(e2))); sminl = fminf(sminl, mu);
    } else {
      if (fabsf(e1) <= tol*fabsf(d1)) { e1 = 0.0f; continue; }
      float mu = fabsf(d3); sminl = mu;
      if (fabsf(e2) <= tol*mu) { e2 = 0.0f; continue; }
      mu = fabsf(d2)*(mu/(mu + fabsf(e2))); sminl = fminf(sminl, mu);
      if (fabsf(e1) <= tol*mu) { e1 = 0.0f; continue; }
      mu = fabsf(d1)*(mu/(mu + fabsf(e1))); sminl = fminf(sminl, mu);
    }
    oldll = 1; oldm = 3;

    float shift = 0.0f, rdum;
    if (!(3.0f*tol*(sminl/smax) <= fmaxf(eps, 0.01f*tol))) {
      float sll;
      if (idir == 1) { sll = fabsf(d1); slas2_f(d2, e2, d3, shift, rdum); }
      else           { sll = fabsf(d3); slas2_f(d1, e1, d2, shift, rdum); }
      if (sll > 0.0f) { float qq = shift/sll; if (qq*qq < eps) shift = 0.0f; }
    }

    if (shift == 0.0f) {
      if (idir == 1) {
        float cs = 1.0f, oldcs = 1.0f, sn = 0.0f, oldsn = 0.0f, r;
        float c10, s10, c20, s20, c11, s11, c21, s21;
        slartg_f(d1*cs, e1, cs, sn, r);
        slartg_f(oldcs*r, d2*sn, oldcs, oldsn, d1);
        c10 = cs; s10 = sn; c20 = oldcs; s20 = oldsn;
        slartg_f(d2*cs, e2, cs, sn, r);
        e1 = oldsn*r;
        slartg_f(oldcs*r, d3*sn, oldcs, oldsn, d2);
        c11 = cs; s11 = sn; c21 = oldcs; s21 = oldsn;
        float h = d3*cs;
        d3 = h*oldcs; e2 = h*oldsn;
        rotr<0,1>(vt, c10, s10); rotr<1,2>(vt, c11, s11);
        rotc<0,1>(u,  c20, s20); rotc<1,2>(u,  c21, s21);
        if (fabsf(e2) <= thresh) e2 = 0.0f;
      } else {
        float cs = 1.0f, oldcs = 1.0f, sn = 0.0f, oldsn = 0.0f, r;
        float c10, s10, c20, s20, c11, s11, c21, s21;
        slartg_f(d3*cs, e2, cs, sn, r);
        slartg_f(oldcs*r, d2*sn, oldcs, oldsn, d3);
        c11 = cs; s11 = -sn; c21 = oldcs; s21 = -oldsn;
        slartg_f(d2*cs, e1, cs, sn, r);
        e2 = oldsn*r;
        slartg_f(oldcs*r, d1*sn, oldcs, oldsn, d2);
        c10 = cs; s10 = -sn; c20 = oldcs; s20 = -oldsn;
        float h = d1*cs;
        d1 = h*oldcs; e1 = h*oldsn;
        rotr<1,2>(vt, c21, s21); rotr<0,1>(vt, c20, s20);
        rotc<1,2>(u,  c11, s11); rotc<0,1>(u,  c10, s10);
        if (fabsf(e1) <= thresh) e1 = 0.0f;
      }
    } else {
      if (idir == 1) {
        float f = (fabsf(d1) - shift)*(copysignf(1.0f, d1) + shift/d1);
        float g = e1, cr, sr, cl, sl, r;
        float c10, s10, c20, s20, c11, s11, c21, s21;
        slartg_f(f, g, cr, sr, r);
        f = cr*d1 + sr*e1;  e1 = cr*e1 - sr*d1;
        g = sr*d2;  d2 = cr*d2;
        slartg_f(f, g, cl, sl, r);
        d1 = r;  f = cl*e1 + sl*d2;  d2 = cl*d2 - sl*e1;
        g = sl*e2;  e2 = cl*e2;
        c10 = cr; s10 = sr; c20 = cl; s20 = sl;
        slartg_f(f, g, cr, sr, r);
        e1 = r;
        f = cr*d2 + sr*e2;  e2 = cr*e2 - sr*d2;
        g = sr*d3;  d3 = cr*d3;
        slartg_f(f, g, cl, sl, r);
        d2 = r;  f = cl*e2 + sl*d3;  d3 = cl*d3 - sl*e2;
        c11 = cr; s11 = sr; c21 = cl; s21 = sl;
        e2 = f;
        rotr<0,1>(vt, c10, s10); rotr<1,2>(vt, c11, s11);
        rotc<0,1>(u,  c20, s20); rotc<1,2>(u,  c21, s21);
        if (fabsf(e2) <= thresh) e2 = 0.0f;
      } else {
        float f = (fabsf(d3) - shift)*(copysignf(1.0f, d3) + shift/d3);
        float g = e2, cr, sr, cl, sl, r;
        float c10, s10, c20, s20, c11, s11, c21, s21;
        slartg_f(f, g, cr, sr, r);
        f = cr*d3 + sr*e2;  e2 = cr*e2 - sr*d3;
        g = sr*d2;  d2 = cr*d2;
        slartg_f(f, g, cl, sl, r);
        d3 = r;  f = cl*e2 + sl*d2;  d2 = cl*d2 - sl*e2;
        g = sl*e1;  e1 = cl*e1;
        c11 = cr; s11 = -sr; c21 = cl; s21 = -sl;
        slartg_f(f, g, cr, sr, r);
        e2 = r;
        f = cr*d2 + sr*e1;  e1 = cr*e1 - sr*d2;
        g = sr*d1;  d1 = cr*d1;
        slartg_f(f, g, cl, sl, r);
        d2 = r;  f = cl*e1 + sl*d1;  d1 = cl*d1 - sl*e1;
        c10 = cr; s10 = -sr; c20 = cl; s20 = -sl;
        e1 = f;
        if (fabsf(e1) <= thresh) e1 = 0.0f;
        rotr<1,2>(vt, c21, s21); rotr<0,1>(vt, c20, s20);
        rotc<1,2>(u,  c11, s11); rotc<0,1>(u,  c10, s10);
      }
    }
  }

  if (d1 < 0.0f) { d1 = -d1; vt[0][0] = -vt[0][0]; vt[0][1] = -vt[0][1]; vt[0][2] = -vt[0][2]; }
  if (d2 < 0.0f) { d2 = -d2; vt[1][0] = -vt[1][0]; vt[1][1] = -vt[1][1]; vt[1][2] = -vt[1][2]; }
  if (d3 < 0.0f) { d3 = -d3; vt[2][0] = -vt[2][0]; vt[2][1] = -vt[2][1]; vt[2][2] = -vt[2][2]; }

  { // pass 1: min of (d1,d2,d3) -> slot 3
    int isub = 1; float smn = d1;
    if (d2 <= smn) { isub = 2; smn = d2; }
    if (d3 <= smn) { isub = 3; smn = d3; }
    if (isub == 1)      { d1 = d3; d3 = smn; swaprow<0,2>(vt); swapcol<0,2>(u); }
    else if (isub == 2) { d2 = d3; d3 = smn; swaprow<1,2>(vt); swapcol<1,2>(u); }
  }
  { // pass 2: min of (d1,d2) -> slot 2
    int isub = 1; float smn = d1;
    if (d2 <= smn) { isub = 2; smn = d2; }
    if (isub == 1) { d1 = d2; d2 = smn; swaprow<0,1>(vt); swapcol<0,1>(u); }
  }
}

__device__ __forceinline__ void svd3_gesdd(const float Ain[3][3], float u[3][3], float vt[3][3]) {
  float a[3][3];
#pragma unroll
  for (int i = 0; i < 3; ++i)
#pragma unroll
    for (int j = 0; j < 3; ++j) a[i][j] = Ain[i][j];

  float d1, d2, d3, e1, e2;
  float tq0 = 0.f, tq1 = 0.f, tp0 = 0.f;
  float v0a = 0.f, v0b = 0.f, v1a = 0.f, p0a = 0.f;

  {
    float alpha = a[0][0];
    float xn = sqrtf(a[1][0]*a[1][0] + a[2][0]*a[2][0]);
    if (xn == 0.0f) { tq0 = 0.0f; d1 = alpha; }
    else {
      float beta = -copysignf(sqrtf(alpha*alpha + xn*xn), alpha);
      tq0 = (beta - alpha)/beta;
      float sc = 1.0f/(alpha - beta);
      v0a = a[1][0]*sc; v0b = a[2][0]*sc;
      d1 = beta;
    }
#pragma unroll
    for (int j = 1; j < 3; ++j) {
      float w = (a[0][j] + v0a*a[1][j] + v0b*a[2][j])*tq0;
      a[0][j] -= w; a[1][j] -= w*v0a; a[2][j] -= w*v0b;
    }
  }
  {
    float alpha = a[0][1];
    float xn = fabsf(a[0][2]);
    if (xn == 0.0f) { tp0 = 0.0f; e1 = alpha; }
    else {
      float beta = -copysignf(sqrtf(alpha*alpha + xn*xn), alpha);
      tp0 = (beta - alpha)/beta;
      p0a = a[0][2]/(alpha - beta);
      e1 = beta;
    }
#pragma unroll
    for (int i = 1; i < 3; ++i) {
      float w = (a[i][1] + p0a*a[i][2])*tp0;
      a[i][1] -= w; a[i][2] -= w*p0a;
    }
  }
  {
    float alpha = a[1][1];
    float xn = fabsf(a[2][1]);
    if (xn == 0.0f) { tq1 = 0.0f; d2 = alpha; }
    else {
      float beta = -copysignf(sqrtf(alpha*alpha + xn*xn), alpha);
      tq1 = (beta - alpha)/beta;
      v1a = a[2][1]/(alpha - beta);
      d2 = beta;
    }
    float w = (a[1][2] + v1a*a[2][2])*tq1;
    a[1][2] -= w; a[2][2] -= w*v1a;
  }
  e2 = a[1][2];
  d3 = a[2][2];

  float ub[3][3] = {{1,0,0},{0,1,0},{0,0,1}};
  float vb[3][3] = {{1,0,0},{0,1,0},{0,0,1}};
  sbdsqr3_reg(d1, d2, d3, e1, e2, ub, vb);

#pragma unroll
  for (int j = 0; j < 3; ++j) {
    float w = (ub[1][j] + v1a*ub[2][j])*tq1;
    ub[1][j] -= w; ub[2][j] -= w*v1a;
  }
#pragma unroll
  for (int j = 0; j < 3; ++j) {
    float w = (ub[0][j] + v0a*ub[1][j] + v0b*ub[2][j])*tq0;
    ub[0][j] -= w; ub[1][j] -= w*v0a; ub[2][j] -= w*v0b;
  }
#pragma unroll
  for (int i = 0; i < 3; ++i) {
    float w = (vb[i][1] + p0a*vb[i][2])*tp0;
    vb[i][1] -= w; vb[i][2] -= w*p0a;
  }
#pragma unroll
  for (int i = 0; i < 3; ++i)
#pragma unroll
    for (int j = 0; j < 3; ++j) { u[i][j] = ub[i][j]; vt[i][j] = vb[i][j]; }
}

// =============================================================================
// bf16 helpers (RNE, manual — verified since round 1)
// =============================================================================
__device__ __forceinline__ unsigned int f2bf(float x) {
  unsigned int u = __float_as_uint(x);
  return (u + 0x7FFFu + ((u >> 16) & 1u)) >> 16;
}
__device__ __forceinline__ float bf2f(unsigned int h) {
  return __uint_as_float(h << 16);
}

// =============================================================================
// ROUND 16: full-rate-VALU exp2 (P is rounded to bf16 right after, so hw-exact
// v_exp_f32 — 1/16-rate trans pipe, ~27us/CU saturated & occupancy-invariant —
// is waste). x = n + f, cubic interpolant of 2^f on [0,1] (nodes 0,1/3,2/3,1;
// rel err <= 1.7e-4 << bf16 half-ulp 2e-3), exact 2^n via exponent-field add.
// 8 full-rate ops vs 64 trans cycles. Scores |x| <~ 9 => no overflow/denormal.
// =============================================================================
__device__ __forceinline__ float fexp2(float x) {
  float xf = floorf(x);
  float f = x - xf;
  float p = __builtin_fmaf(__builtin_fmaf(__builtin_fmaf(
              0.0790185f, f, 0.2249975f), f, 0.695984f), f, 1.0f);
  int n = (int)xf;
  return __uint_as_float(__float_as_uint(p) + ((unsigned int)n << 23));
}

// =============================================================================
// Kernel 0: pack. (round 12, unchanged)
// =============================================================================
__global__ __launch_bounds__(128)
void pack_kernel(const float* __restrict__ srcE, const float* __restrict__ tgtE,
                 const float* __restrict__ tgt,
                 unsigned short* __restrict__ Qp, unsigned short* __restrict__ Kp,
                 unsigned short* __restrict__ Vt4) {
  const int g = blockIdx.x*128 + threadIdx.x;   // 32768 = 16*2048
  const int b = g >> 11, n = g & 2047;
  const float* qs = srcE + (size_t)b*16*2048 + n;
  const float* ks = tgtE + (size_t)b*16*2048 + n;
  const float QSCALE = 0.25f * 1.44269504088896340736f;

  unsigned short qrow[32], krow[32];
#pragma unroll
  for (int dd = 0; dd < 16; ++dd) {
    float q = qs[dd*2048] * QSCALE;
    unsigned int qh = f2bf(q);
    qrow[dd] = (unsigned short)qh; qrow[16+dd] = (unsigned short)f2bf(q - bf2f(qh));
    float k = ks[dd*2048];
    unsigned int kh = f2bf(k);
    krow[dd] = (unsigned short)kh; krow[16+dd] = (unsigned short)f2bf(k - bf2f(kh));
  }
  uint4* qdst = (uint4*)(Qp + (size_t)g*32);
  uint4* kdst = (uint4*)(Kp + (size_t)g*32);
#pragma unroll
  for (int i = 0; i < 4; ++i) { qdst[i] = ((uint4*)qrow)[i]; kdst[i] = ((uint4*)krow)[i]; }

  const float* vp = tgt + (size_t)b*3*2048 + n;
  unsigned short* wb = Vt4 + (size_t)b*4*2048;
  wb[n]          = 0x3F80;             // ones column (j=0)
  wb[2048 + n]   = (unsigned short)f2bf(vp[0]);
  wb[2*2048 + n] = (unsigned short)f2bf(vp[2048]);
  wb[3*2048 + n] = (unsigned short)f2bf(vp[4096]);
}

// =============================================================================
// Kernel 1: MFMA flash attention; PV + softmax-sum via MFMA. Round-12 geometry
// (grid 512, 64 n/block, 4 n-tiles); ONLY change: exp2 -> fexp2 (VALU).
// =============================================================================
__global__ __launch_bounds__(512, 4)
void corr_kernel(const unsigned short* __restrict__ Qp, const unsigned short* __restrict__ Kp,
                 const unsigned short* __restrict__ Vt4, const float* __restrict__ src,
                 float* __restrict__ ws) {
  const int bid = blockIdx.x;
  const int b   = bid & 15;
  const int nt  = bid >> 4;          // 0..31, 64 n each
  const int tid = threadIdx.x;
  const int w   = tid >> 6;
  const int L   = tid & 63;
  const int lg  = L >> 4;
  const int ll  = L & 15;

  __shared__ __align__(16) char  stage[8*1280];       // 10 KB: per-wave A' staging (80B rows)
  __shared__ __align__(16) float partial[8][64][4];   // 8 KB

  const unsigned short* Qb = Qp + (size_t)b*2048*32;
  const unsigned short* Kb = Kp + (size_t)b*2048*32;
  const unsigned short* Wb = Vt4 + (size_t)b*4*2048;

  const bf16x8 zero8 = {0,0,0,0,0,0,0,0};
  char* my = stage + w*1280;
  char* wr0 = my + ll*80 + lg*8;        // tile0 write slot
  char* wr1 = wr0 + 32;                 // tile1 write slot
  const char* rd = my + ll*80 + lg*16;  // A'-frag read slot (16B aligned: 80=16*5)

  // ---- Q-fragments for this block's 4 n-tiles ----
  bf16x8 bq1[4], bq2[4];
#pragma unroll
  for (int t2 = 0; t2 < 4; ++t2) {
    const unsigned short* qr = Qb + (size_t)(nt*64 + t2*16 + ll)*32;
    bq1[t2] = *(const bf16x8*)(qr + (lg & 1)*8);
    bf16x8 lo = *(const bf16x8*)(qr + 16 + (lg & 1)*8);
    bq2[t2] = (lg < 2) ? lo : zero8;
  }

  f32x4 accp[4];
#pragma unroll
  for (int t2 = 0; t2 < 4; ++t2) accp[t2] = (f32x4){0.f, 0.f, 0.f, 0.f};

  for (int p = w; p < 64; p += 8) {
    const unsigned short* ar = Kb + (size_t)(p*32 + ll)*32;
    bf16x8 a0 = *(const bf16x8*)(ar + lg*8);            // m-tile 2p
    bf16x8 a1 = *(const bf16x8*)(ar + 16*32 + lg*8);    // m-tile 2p+1
    bf16x8 wv = zero8;                                  // W B-frag (cols>=4 zero)
    if (ll < 4) wv = *(const bf16x8*)(Wb + (size_t)ll*2048 + p*32 + lg*8);

#pragma unroll
    for (int t2 = 0; t2 < 4; ++t2) {
      f32x4 c0 = (f32x4){0.f,0.f,0.f,0.f};
      f32x4 c1 = (f32x4){0.f,0.f,0.f,0.f};
      c0 = __builtin_amdgcn_mfma_f32_16x16x32_bf16(a0, bq1[t2], c0, 0, 0, 0);
      c0 = __builtin_amdgcn_mfma_f32_16x16x32_bf16(a0, bq2[t2], c0, 0, 0, 0);
      c1 = __builtin_amdgcn_mfma_f32_16x16x32_bf16(a1, bq1[t2], c1, 0, 0, 0);
      c1 = __builtin_amdgcn_mfma_f32_16x16x32_bf16(a1, bq2[t2], c1, 0, 0, 0);
      // P = exp2(scores) via full-rate VALU poly; C-frag: row m_loc=lg*4+r, col n=ll
      float e0 = fexp2(c0.x), e1 = fexp2(c0.y);
      float e2 = fexp2(c0.z), e3 = fexp2(c0.w);
      float f0 = fexp2(c1.x), f1 = fexp2(c1.y);
      float f2 = fexp2(c1.z), f3 = fexp2(c1.w);
      // pack to bf16 pairs (lo = even r) and stage into A' layout
      *(uint2*)wr0 = make_uint2(f2bf(e0) | (f2bf(e1) << 16),
                                f2bf(e2) | (f2bf(e3) << 16));
      *(uint2*)wr1 = make_uint2(f2bf(f0) | (f2bf(f1) << 16),
                                f2bf(f2) | (f2bf(f3) << 16));
      bf16x8 pa = *(const bf16x8*)rd;   // A'[row=ll][k=lg*8..+7]
      // PV: X[n][j] += P^T x W   (j: 0=sumE, 1..3 = sum e*v)
      accp[t2] = __builtin_amdgcn_mfma_f32_16x16x32_bf16(pa, wv, accp[t2], 0, 0, 0);
    }
  }

  // ---- write per-wave partials: X[j=ll][n] for ll<4 ----
  if (ll < 4) {
#pragma unroll
    for (int t2 = 0; t2 < 4; ++t2) {
      int nb = t2*16 + lg*4;
      partial[w][nb+0][ll] = accp[t2].x;
      partial[w][nb+1][ll] = accp[t2].y;
      partial[w][nb+2][ll] = accp[t2].z;
      partial[w][nb+3][ll] = accp[t2].w;
    }
  }
  __syncthreads();

  // ---- per-n finish + 15-value single-wave reduction (wave 0 only) ----
  if (tid < 64) {
    float4 s4 = make_float4(0.f, 0.f, 0.f, 0.f);
#pragma unroll
    for (int w2 = 0; w2 < 8; ++w2) {
      float4 pq = *(const float4*)&partial[w2][tid][0];
      s4.x += pq.x; s4.y += pq.y; s4.z += pq.z; s4.w += pq.w;
    }
    float inv = 1.0f / s4.x;
    float c0 = s4.y*inv, c1 = s4.z*inv, c2 = s4.w*inv;
    const int n = nt*64 + tid;
    const float* sp = src + (size_t)b*3*2048;
    float s0v = sp[n], s1v = sp[2048+n], s2v = sp[4096+n];
    float vals[15] = { c0, c1, c2, s0v, s1v, s2v,
                       s0v*c0, s0v*c1, s0v*c2,
                       s1v*c0, s1v*c1, s1v*c2,
                       s2v*c0, s2v*c1, s2v*c2 };
#pragma unroll
    for (int k = 0; k < 15; ++k) {
      float v = vals[k];
      v += __shfl_xor(v, 1);  v += __shfl_xor(v, 2);  v += __shfl_xor(v, 4);
      v += __shfl_xor(v, 8);  v += __shfl_xor(v, 16); v += __shfl_xor(v, 32);
      vals[k] = v;
    }
    if (tid == 0) {
#pragma unroll
      for (int k = 0; k < 15; ++k) ws[bid*16 + k] = vals[k];
    }
  }
}

// =============================================================================
// Kernel 2: 16 BLOCKS x 64 threads — one batch per block (round 12 layout).
// =============================================================================
__global__ __launch_bounds__(64)
void finalize_kernel(const float* __restrict__ ws, float* __restrict__ out) {
  const int b = blockIdx.x;
  const int L = threadIdx.x;

  float a = 0.0f;
  if (L < 15) {
#pragma unroll
    for (int ntile = 0; ntile < 32; ++ntile)
      a += ws[(ntile*16 + b)*16 + L];
  }
  float acc[15];
#pragma unroll
  for (int k = 0; k < 15; ++k) acc[k] = __shfl(a, k);

  if (L == 0) {
    const float invN = 1.0f/2048.0f;
    float Sc[3] = {acc[0], acc[1], acc[2]};
    float Ss[3] = {acc[3], acc[4], acc[5]};
    float cm[3] = {Sc[0]*invN, Sc[1]*invN, Sc[2]*invN};
    float sm[3] = {Ss[0]*invN, Ss[1]*invN, Ss[2]*invN};

    float A[3][3];
#pragma unroll
    for (int i = 0; i < 3; ++i)
#pragma unroll
      for (int j = 0; j < 3; ++j)
        A[i][j] = acc[6 + i*3 + j] - Ss[i]*cm[j];

    float u[3][3], vt[3][3];
    svd3_gesdd(A, u, vt);

    float R[3][3];
#pragma unroll
    for (int i = 0; i < 3; ++i)
#pragma unroll
      for (int k = 0; k < 3; ++k)
        R[i][k] = vt[i][0]*u[k][0] + vt[i][1]*u[k][1] + vt[i][2]*u[k][2];

    float det = R[0][0]*(R[1][1]*R[2][2] - R[1][2]*R[2][1])
              - R[0][1]*(R[1][0]*R[2][2] - R[1][2]*R[2][0])
              + R[0][2]*(R[1][0]*R[2][1] - R[1][1]*R[2][0]);

    if (det < 0.0f) {
#pragma unroll
      for (int i = 0; i < 3; ++i)
#pragma unroll
        for (int k = 0; k < 3; ++k)
          R[i][k] -= 2.0f*vt[i][2]*u[k][2];
    }

    float tv[3];
#pragma unroll
    for (int i = 0; i < 3; ++i)
      tv[i] = -(R[i][0]*sm[0] + R[i][1]*sm[1] + R[i][2]*sm[2]) + cm[i];

#pragma unroll
    for (int i = 0; i < 3; ++i)
#pragma unroll
      for (int j = 0; j < 3; ++j)
        out[b*9 + i*3 + j] = R[i][j];
#pragma unroll
    for (int i = 0; i < 3; ++i)
      out[144 + b*3 + i] = tv[i];
  }
}

extern "C" void kernel_launch(void* const* d_in, const int* in_sizes, int n_in,
                              void* d_out, int out_size, void* d_ws, size_t ws_size,
                              hipStream_t stream) {
  const float* srcE = (const float*)d_in[0];
  const float* tgtE = (const float*)d_in[1];
  const float* src  = (const float*)d_in[2];
  const float* tgt  = (const float*)d_in[3];
  float* out = (float*)d_out;

  // ws layout: [0,32KB) partials | Qp 2MB | Kp 2MB | Vt4 256KB
  float* part = (float*)d_ws;
  unsigned short* Qp  = (unsigned short*)((char*)d_ws + 32768);
  unsigned short* Kp  = (unsigned short*)((char*)d_ws + 32768 + (size_t)16*2048*32*2);
  unsigned short* Vt4 = (unsigned short*)((char*)d_ws + 32768 + (size_t)2*16*2048*32*2);

  hipLaunchKernelGGL(pack_kernel, dim3(256), dim3(128), 0, stream, srcE, tgtE, tgt, Qp, Kp, Vt4);
  hipLaunchKernelGGL(corr_kernel, dim3(512), dim3(512), 0, stream, Qp, Kp, Vt4, src, part);
  hipLaunchKernelGGL(finalize_kernel, dim3(16), dim3(64), 0, stream, part, out);
}

// Round 17
// 39.052 us; speedup vs baseline: 1.1919x; 1.1919x over previous
//
#include <hip/hip_runtime.h>
#include <math.h>

// LAPACK >= 3.10 slartg convention (c >= 0). Flip to 0 to emulate <= 3.9.
#define NEW_SLARTG 1

typedef __attribute__((ext_vector_type(8))) short bf16x8;
typedef __attribute__((ext_vector_type(4))) float f32x4;

// =============================================================================
// LAPACK sgesdd emulation for 3x3 (f32), faithful sign conventions.
// FULLY SCALARIZED (round 10); 16 blocks x 1 SVD (round 12) — unchanged.
// =============================================================================

__device__ __forceinline__ void slartg_f(float f, float g, float& c, float& s, float& r) {
#if NEW_SLARTG
  if (g == 0.0f) { c = 1.0f; s = 0.0f; r = f; }
  else if (f == 0.0f) { c = 0.0f; s = copysignf(1.0f, g); r = fabsf(g); }
  else {
    float d = sqrtf(f*f + g*g);
    c = fabsf(f) / d;
    r = copysignf(d, f);
    s = g / r;
  }
#else
  if (g == 0.0f) { c = 1.0f; s = 0.0f; r = f; }
  else if (f == 0.0f) { c = 0.0f; s = 1.0f; r = g; }
  else {
    float d = sqrtf(f*f + g*g);
    c = f / d; s = g / d; r = d;
    if (fabsf(f) > fabsf(g) && c < 0.0f) { c = -c; s = -s; r = -r; }
  }
#endif
}

__device__ __forceinline__ void slas2_f(float f, float g, float h, float& ssmin, float& ssmax) {
  float fa = fabsf(f), ga = fabsf(g), ha = fabsf(h);
  float fhmn = fminf(fa, ha), fhmx = fmaxf(fa, ha);
  if (fhmn == 0.0f) {
    ssmin = 0.0f;
    if (fhmx == 0.0f) ssmax = ga;
    else {
      float mn = fminf(fhmx, ga), mx = fmaxf(fhmx, ga);
      float qq = mn / mx;
      ssmax = mx * sqrtf(1.0f + qq*qq);
    }
  } else {
    if (ga < fhmx) {
      float as_ = 1.0f + fhmn/fhmx;
      float at_ = (fhmx - fhmn)/fhmx;
      float au_ = ga/fhmx; au_ = au_*au_;
      float c = 2.0f/(sqrtf(as_*as_ + au_) + sqrtf(at_*at_ + au_));
      ssmin = fhmn*c;
      ssmax = fhmx/c;
    } else {
      float au_ = fhmx/ga;
      if (au_ == 0.0f) {
        ssmin = (fhmn*fhmx)/ga;
        ssmax = ga;
      } else {
        float as_ = 1.0f + fhmn/fhmx;
        float at_ = (fhmx - fhmn)/fhmx;
        float t1 = as_*au_, t2 = at_*au_;
        float c = 1.0f/(sqrtf(1.0f + t1*t1) + sqrtf(1.0f + t2*t2));
        ssmin = (fhmn*c)*au_;
        ssmin = ssmin + ssmin;
        ssmax = ga/(c + c);
      }
    }
  }
}

__device__ __forceinline__ void slasv2_f(float f, float g, float h,
                         float& ssmin, float& ssmax,
                         float& snr, float& csr, float& snl, float& csl) {
  const float eps = 5.9604645e-08f;
  float ft = f, fa = fabsf(f), ht = h, ha = fabsf(h);
  int pmax = 1;
  bool swap_ = (ha > fa);
  if (swap_) {
    pmax = 3;
    float tq = ft; ft = ht; ht = tq;
    tq = fa; fa = ha; ha = tq;
  }
  float gt = g, ga = fabsf(g);
  float clt = 0.f, crt = 0.f, slt = 0.f, srt = 0.f;
  if (ga == 0.0f) {
    ssmin = ha; ssmax = fa;
    clt = 1.0f; crt = 1.0f; slt = 0.0f; srt = 0.0f;
  } else {
    bool gasmal = true;
    if (ga > fa) {
      pmax = 2;
      if ((fa/ga) < eps) {
        gasmal = false;
        ssmax = ga;
        ssmin = (ha > 1.0f) ? (fa/(ga/ha)) : ((fa/ga)*ha);
        clt = 1.0f; slt = ht/gt; srt = 1.0f; crt = ft/gt;
      }
    }
    if (gasmal) {
      float dd = fa - ha;
      float l = (dd == fa) ? 1.0f : (dd/fa);
      float mr = gt/ft;
      float t = 2.0f - l;
      float mm2 = mr*mr, tt = t*t;
      float s_ = sqrtf(tt + mm2);
      float r_ = (l == 0.0f) ? fabsf(mr) : sqrtf(l*l + mm2);
      float a_ = 0.5f*(s_ + r_);
      ssmin = ha/a_;
      ssmax = fa*a_;
      if (mm2 == 0.0f) {
        if (l == 0.0f) t = copysignf(2.0f, ft)*copysignf(1.0f, gt);
        else t = gt/copysignf(dd, ft) + mr/t;
      } else {
        t = (mr/(s_ + t) + mr/(r_ + l))*(1.0f + a_);
      }
      float l2 = sqrtf(t*t + 4.0f);
      crt = 2.0f/l2;
      srt = t/l2;
      clt = (crt + srt*mr)/a_;
      slt = (ht/ft)*srt/a_;
    }
  }
  if (swap_) { csl = srt; snl = crt; csr = slt; snr = clt; }
  else       { csl = clt; snl = slt; csr = crt; snr = srt; }
  float tsign = 0.f;
  if (pmax == 1) tsign = copysignf(1.0f, csr)*copysignf(1.0f, csl)*copysignf(1.0f, f);
  if (pmax == 2) tsign = copysignf(1.0f, snr)*copysignf(1.0f, csl)*copysignf(1.0f, g);
  if (pmax == 3) tsign = copysignf(1.0f, snr)*copysignf(1.0f, snl)*copysignf(1.0f, h);
  ssmax = copysignf(ssmax, tsign);
  ssmin = copysignf(ssmin, tsign*copysignf(1.0f, f)*copysignf(1.0f, h));
}

// rotation / swap helpers with COMPILE-TIME indices (template params)
template<int R1, int R2>
__device__ __forceinline__ void rotr(float mt[3][3], float c, float s) {
#pragma unroll
  for (int k = 0; k < 3; ++k) {
    float x = mt[R1][k], y = mt[R2][k];
    mt[R1][k] = c*x + s*y;
    mt[R2][k] = c*y - s*x;
  }
}
template<int C1, int C2>
__device__ __forceinline__ void rotc(float mt[3][3], float c, float s) {
#pragma unroll
  for (int k = 0; k < 3; ++k) {
    float x = mt[k][C1], y = mt[k][C2];
    mt[k][C1] = c*x + s*y;
    mt[k][C2] = c*y - s*x;
  }
}
template<int R1, int R2>
__device__ __forceinline__ void swaprow(float mt[3][3]) {
#pragma unroll
  for (int k = 0; k < 3; ++k) { float t = mt[R1][k]; mt[R1][k] = mt[R2][k]; mt[R2][k] = t; }
}
template<int C1, int C2>
__device__ __forceinline__ void swapcol(float mt[3][3]) {
#pragma unroll
  for (int k = 0; k < 3; ++k) { float t = mt[k][C1]; mt[k][C1] = mt[k][C2]; mt[k][C2] = t; }
}

// SBDSQR specialized for n=3 upper bidiagonal, all-register state.
__device__ __forceinline__ void sbdsqr3_reg(float& d1, float& d2, float& d3,
                                            float& e1, float& e2,
                                            float u[3][3], float vt[3][3]) {
  const float eps  = 5.9604645e-08f;
  const float unfl = 1.17549435e-38f;
  const float tol  = 10.0f*eps;

  float sminoa = fabsf(d1);
  if (sminoa != 0.0f) {
    float mu = sminoa;
    mu = fabsf(d2)*(mu/(mu + fabsf(e1)));
    sminoa = fminf(sminoa, mu);
    if (sminoa != 0.0f) {
      mu = fabsf(d3)*(mu/(mu + fabsf(e2)));
      sminoa = fminf(sminoa, mu);
    }
  }
  sminoa = sminoa / sqrtf(3.0f);
  float thresh = fmaxf(tol*sminoa, 54.0f*unfl);

  int m = 3, oldll = -1, oldm = -1, idir = 0;
  int guard = 0;
  while (m > 1 && ++guard < 200) {
    if (m == 2) {
      if (fabsf(e1) <= thresh) { e1 = 0.0f; m = 1; continue; }
      float sigmn, sigmx, sinr, cosr, sinl, cosl;
      slasv2_f(d1, e1, d2, sigmn, sigmx, sinr, cosr, sinl, cosl);
      d1 = sigmx; d2 = sigmn; e1 = 0.0f;
      rotr<0,1>(vt, cosr, sinr);
      rotc<0,1>(u,  cosl, sinl);
      m = 0; continue;
    }
    // ---- m == 3 ----
    float smax = fabsf(d3);
    if (fabsf(e2) <= thresh) { e2 = 0.0f; m = 2; continue; }
    smax = fmaxf(smax, fmaxf(fabsf(d2), fabsf(e2)));
    if (fabsf(e1) <= thresh) {
      e1 = 0.0f;
      float sigmn, sigmx, sinr, cosr, sinl, cosl;
      slasv2_f(d2, e2, d3, sigmn, sigmx, sinr, cosr, sinl, cosl);
      d2 = sigmx; d3 = sigmn; e2 = 0.0f;
      rotr<1,2>(vt, cosr, sinr);
      rotc<1,2>(u,  cosl, sinl);
      m = 1; continue;
    }
    smax = fmaxf(smax, fmaxf(fabsf(d1), fabsf(e1)));

    if (1 > oldm || 3 < oldll)
      idir = (fabsf(d1) >= fabsf(d3)) ? 1 : 2;

    float sminl = 0.0f;
    if (idir == 1) {
      if (fabsf(e2) <= tol*fabsf(d3)) { e2 = 0.0f; continue; }
      float mu = fabsf(d1); sminl = mu;
      if (fabsf(e1) <= tol*mu) { e1 = 0.0f; continue; }
      mu = fabsf(d2)*(mu/(mu + fabsf(e1))); sminl = fminf(sminl, mu);
      if (fabsf(e2) <= tol*mu) { e2 = 0.0f; continue; }
      mu = fabsf(d3)*(mu/(mu + fabsf(e2))); sminl = fminf(sminl, mu);
    } else {
      if (fabsf(e1) <= tol*fabsf(d1)) { e1 = 0.0f; continue; }
      float mu = fabsf(d3); sminl = mu;
      if (fabsf(e2) <= tol*mu) { e2 = 0.0f; continue; }
      mu = fabsf(d2)*(mu/(mu + fabsf(e2))); sminl = fminf(sminl, mu);
      if (fabsf(e1) <= tol*mu) { e1 = 0.0f; continue; }
      mu = fabsf(d1)*(mu/(mu + fabsf(e1))); sminl = fminf(sminl, mu);
    }
    oldll = 1; oldm = 3;

    float shift = 0.0f, rdum;
    if (!(3.0f*tol*(sminl/smax) <= fmaxf(eps, 0.01f*tol))) {
      float sll;
      if (idir == 1) { sll = fabsf(d1); slas2_f(d2, e2, d3, shift, rdum); }
      else           { sll = fabsf(d3); slas2_f(d1, e1, d2, shift, rdum); }
      if (sll > 0.0f) { float qq = shift/sll; if (qq*qq < eps) shift = 0.0f; }
    }

    if (shift == 0.0f) {
      if (idir == 1) {
        float cs = 1.0f, oldcs = 1.0f, sn = 0.0f, oldsn = 0.0f, r;
        float c10, s10, c20, s20, c11, s11, c21, s21;
        slartg_f(d1*cs, e1, cs, sn, r);
        slartg_f(oldcs*r, d2*sn, oldcs, oldsn, d1);
        c10 = cs; s10 = sn; c20 = oldcs; s20 = oldsn;
        slartg_f(d2*cs, e2, cs, sn, r);
        e1 = oldsn*r;
        slartg_f(oldcs*r, d3*sn, oldcs, oldsn, d2);
        c11 = cs; s11 = sn; c21 = oldcs; s21 = oldsn;
        float h = d3*cs;
        d3 = h*oldcs; e2 = h*oldsn;
        rotr<0,1>(vt, c10, s10); rotr<1,2>(vt, c11, s11);
        rotc<0,1>(u,  c20, s20); rotc<1,2>(u,  c21, s21);
        if (fabsf(e2) <= thresh) e2 = 0.0f;
      } else {
        float cs = 1.0f, oldcs = 1.0f, sn = 0.0f, oldsn = 0.0f, r;
        float c10, s10, c20, s20, c11, s11, c21, s21;
        slartg_f(d3*cs, e2, cs, sn, r);
        slartg_f(oldcs*r, d2*sn, oldcs, oldsn, d3);
        c11 = cs; s11 = -sn; c21 = oldcs; s21 = -oldsn;
        slartg_f(d2*cs, e1, cs, sn, r);
        e2 = oldsn*r;
        slartg_f(oldcs*r, d1*sn, oldcs, oldsn, d2);
        c10 = cs; s10 = -sn; c20 = oldcs; s20 = -oldsn;
        float h = d1*cs;
        d1 = h*oldcs; e1 = h*oldsn;
        rotr<1,2>(vt, c21, s21); rotr<0,1>(vt, c20, s20);
        rotc<1,2>(u,  c11, s11); rotc<0,1>(u,  c10, s10);
        if (fabsf(e1) <= thresh) e1 = 0.0f;
      }
    } else {
      if (idir == 1) {
        float f = (fabsf(d1) - shift)*(copysignf(1.0f, d1) + shift/d1);
        float g = e1, cr, sr, cl, sl, r;
        float c10, s10, c20, s20, c11, s11, c21, s21;
        slartg_f(f, g, cr, sr, r);
        f = cr*d1 + sr*e1;  e1 = cr*e1 - sr*d1;
        g = sr*d2;  d2 = cr*d2;
        slartg_f(f, g, cl, sl, r);
        d1 = r;  f = cl*e1 + sl*d2;  d2 = cl*d2 - sl*e1;
        g = sl*e2;  e2 = cl*e2;
        c10 = cr; s10 = sr; c20 = cl; s20 = sl;
        slartg_f(f, g, cr, sr, r);
        e1 = r;
        f = cr*d2 + sr*e2;  e2 = cr*e2 - sr*d2;
        g = sr*d3;  d3 = cr*d3;
        slartg_f(f, g, cl, sl, r);
        d2 = r;  f = cl*e2 + sl*d3;  d3 = cl*d3 - sl*e2;
        c11 = cr; s11 = sr; c21 = cl; s21 = sl;
        e2 = f;
        rotr<0,1>(vt, c10, s10); rotr<1,2>(vt, c11, s11);
        rotc<0,1>(u,  c20, s20); rotc<1,2>(u,  c21, s21);
        if (fabsf(e2) <= thresh) e2 = 0.0f;
      } else {
        float f = (fabsf(d3) - shift)*(copysignf(1.0f, d3) + shift/d3);
        float g = e2, cr, sr, cl, sl, r;
        float c10, s10, c20, s20, c11, s11, c21, s21;
        slartg_f(f, g, cr, sr, r);
        f = cr*d3 + sr*e2;  e2 = cr*e2 - sr*d3;
        g = sr*d2;  d2 = cr*d2;
        slartg_f(f, g, cl, sl, r);
        d3 = r;  f = cl*e2 + sl*d2;  d2 = cl*d2 - sl*e2;
        g = sl*e1;  e1 = cl*e1;
        c11 = cr; s11 = -sr; c21 = cl; s21 = -sl;
        slartg_f(f, g, cr, sr, r);
        e2 = r;
        f = cr*d2 + sr*e1;  e1 = cr*e1 - sr*d2;
        g = sr*d1;  d1 = cr*d1;
        slartg_f(f, g, cl, sl, r);
        d2 = r;  f = cl*e1 + sl*d1;  d1 = cl*d1 - sl*e1;
        c10 = cr; s10 = -sr; c20 = cl; s20 = -sl;
        e1 = f;
        if (fabsf(e1) <= thresh) e1 = 0.0f;
        rotr<1,2>(vt, c21, s21); rotr<0,1>(vt, c20, s20);
        rotc<1,2>(u,  c11, s11); rotc<0,1>(u,  c10, s10);
      }
    }
  }

  if (d1 < 0.0f) { d1 = -d1; vt[0][0] = -vt[0][0]; vt[0][1] = -vt[0][1]; vt[0][2] = -vt[0][2]; }
  if (d2 < 0.0f) { d2 = -d2; vt[1][0] = -vt[1][0]; vt[1][1] = -vt[1][1]; vt[1][2] = -vt[1][2]; }
  if (d3 < 0.0f) { d3 = -d3; vt[2][0] = -vt[2][0]; vt[2][1] = -vt[2][1]; vt[2][2] = -vt[2][2]; }

  { // pass 1: min of (d1,d2,d3) -> slot 3
    int isub = 1; float smn = d1;
    if (d2 <= smn) { isub = 2; smn = d2; }
    if (d3 <= smn) { isub = 3; smn = d3; }
    if (isub == 1)      { d1 = d3; d3 = smn; swaprow<0,2>(vt); swapcol<0,2>(u); }
    else if (isub == 2) { d2 = d3; d3 = smn; swaprow<1,2>(vt); swapcol<1,2>(u); }
  }
  { // pass 2: min of (d1,d2) -> slot 2
    int isub = 1; float smn = d1;
    if (d2 <= smn) { isub = 2; smn = d2; }
    if (isub == 1) { d1 = d2; d2 = smn; swaprow<0,1>(vt); swapcol<0,1>(u); }
  }
}

__device__ __forceinline__ void svd3_gesdd(const float Ain[3][3], float u[3][3], float vt[3][3]) {
  float a[3][3];
#pragma unroll
  for (int i = 0; i < 3; ++i)
#pragma unroll
    for (int j = 0; j < 3; ++j) a[i][j] = Ain[i][j];

  float d1, d2, d3, e1, e2;
  float tq0 = 0.f, tq1 = 0.f, tp0 = 0.f;
  float v0a = 0.f, v0b = 0.f, v1a = 0.f, p0a = 0.f;

  {
    float alpha = a[0][0];
    float xn = sqrtf(a[1][0]*a[1][0] + a[2][0]*a[2][0]);
    if (xn == 0.0f) { tq0 = 0.0f; d1 = alpha; }
    else {
      float beta = -copysignf(sqrtf(alpha*alpha + xn*xn), alpha);
      tq0 = (beta - alpha)/beta;
      float sc = 1.0f/(alpha - beta);
      v0a = a[1][0]*sc; v0b = a[2][0]*sc;
      d1 = beta;
    }
#pragma unroll
    for (int j = 1; j < 3; ++j) {
      float w = (a[0][j] + v0a*a[1][j] + v0b*a[2][j])*tq0;
      a[0][j] -= w; a[1][j] -= w*v0a; a[2][j] -= w*v0b;
    }
  }
  {
    float alpha = a[0][1];
    float xn = fabsf(a[0][2]);
    if (xn == 0.0f) { tp0 = 0.0f; e1 = alpha; }
    else {
      float beta = -copysignf(sqrtf(alpha*alpha + xn*xn), alpha);
      tp0 = (beta - alpha)/beta;
      p0a = a[0][2]/(alpha - beta);
      e1 = beta;
    }
#pragma unroll
    for (int i = 1; i < 3; ++i) {
      float w = (a[i][1] + p0a*a[i][2])*tp0;
      a[i][1] -= w; a[i][2] -= w*p0a;
    }
  }
  {
    float alpha = a[1][1];
    float xn = fabsf(a[2][1]);
    if (xn == 0.0f) { tq1 = 0.0f; d2 = alpha; }
    else {
      float beta = -copysignf(sqrtf(alpha*alpha + xn*xn), alpha);
      tq1 = (beta - alpha)/beta;
      v1a = a[2][1]/(alpha - beta);
      d2 = beta;
    }
    float w = (a[1][2] + v1a*a[2][2])*tq1;
    a[1][2] -= w; a[2][2] -= w*v1a;
  }
  e2 = a[1][2];
  d3 = a[2][2];

  float ub[3][3] = {{1,0,0},{0,1,0},{0,0,1}};
  float vb[3][3] = {{1,0,0},{0,1,0},{0,0,1}};
  sbdsqr3_reg(d1, d2, d3, e1, e2, ub, vb);

#pragma unroll
  for (int j = 0; j < 3; ++j) {
    float w = (ub[1][j] + v1a*ub[2][j])*tq1;
    ub[1][j] -= w; ub[2][j] -= w*v1a;
  }
#pragma unroll
  for (int j = 0; j < 3; ++j) {
    float w = (ub[0][j] + v0a*ub[1][j] + v0b*ub[2][j])*tq0;
    ub[0][j] -= w; ub[1][j] -= w*v0a; ub[2][j] -= w*v0b;
  }
#pragma unroll
  for (int i = 0; i < 3; ++i) {
    float w = (vb[i][1] + p0a*vb[i][2])*tp0;
    vb[i][1] -= w; vb[i][2] -= w*p0a;
  }
#pragma unroll
  for (int i = 0; i < 3; ++i)
#pragma unroll
    for (int j = 0; j < 3; ++j) { u[i][j] = ub[i][j]; vt[i][j] = vb[i][j]; }
}

// =============================================================================
// bf16 helpers (RNE, manual — verified since round 1)
// =============================================================================
__device__ __forceinline__ unsigned int f2bf(float x) {
  unsigned int u = __float_as_uint(x);
  return (u + 0x7FFFu + ((u >> 16) & 1u)) >> 16;
}
__device__ __forceinline__ float bf2f(unsigned int h) {
  return __uint_as_float(h << 16);
}

// =============================================================================
// Kernel 0: pack. (round 12, unchanged)
// =============================================================================
__global__ __launch_bounds__(128)
void pack_kernel(const float* __restrict__ srcE, const float* __restrict__ tgtE,
                 const float* __restrict__ tgt,
                 unsigned short* __restrict__ Qp, unsigned short* __restrict__ Kp,
                 unsigned short* __restrict__ Vt4) {
  const int g = blockIdx.x*128 + threadIdx.x;   // 32768 = 16*2048
  const int b = g >> 11, n = g & 2047;
  const float* qs = srcE + (size_t)b*16*2048 + n;
  const float* ks = tgtE + (size_t)b*16*2048 + n;
  const float QSCALE = 0.25f * 1.44269504088896340736f;

  unsigned short qrow[32], krow[32];
#pragma unroll
  for (int dd = 0; dd < 16; ++dd) {
    float q = qs[dd*2048] * QSCALE;
    unsigned int qh = f2bf(q);
    qrow[dd] = (unsigned short)qh; qrow[16+dd] = (unsigned short)f2bf(q - bf2f(qh));
    float k = ks[dd*2048];
    unsigned int kh = f2bf(k);
    krow[dd] = (unsigned short)kh; krow[16+dd] = (unsigned short)f2bf(k - bf2f(kh));
  }
  uint4* qdst = (uint4*)(Qp + (size_t)g*32);
  uint4* kdst = (uint4*)(Kp + (size_t)g*32);
#pragma unroll
  for (int i = 0; i < 4; ++i) { qdst[i] = ((uint4*)qrow)[i]; kdst[i] = ((uint4*)krow)[i]; }

  const float* vp = tgt + (size_t)b*3*2048 + n;
  unsigned short* wb = Vt4 + (size_t)b*4*2048;
  wb[n]          = 0x3F80;             // ones column (j=0)
  wb[2048 + n]   = (unsigned short)f2bf(vp[0]);
  wb[2*2048 + n] = (unsigned short)f2bf(vp[2048]);
  wb[3*2048 + n] = (unsigned short)f2bf(vp[4096]);
}

// =============================================================================
// Kernel 1: MFMA flash attention; PV + softmax-sum via MFMA.
// ROUND 17: round-12 base (hw exp2 restored) + ONE-STEP PV DEFERRAL with
// double-buffered staging. Round 12's per-step ds_write -> ds_read of the
// SAME bytes forced a ~150-200cy RAW bubble x32 steps/wave (the compiler
// cannot reorder a true RAW). Now step (p,t2) writes buffer (t2&1) and the
// PV for the PREVIOUS step reads the other buffer — its write has had a full
// compute step to land. Deferred accumulator index is compile-time
// (prev=(t2+3)&3); wv of previous p carried in a register; flush after loop.
// Per-accumulator p-order is preserved => BIT-IDENTICAL results to round 12.
// =============================================================================
__global__ __launch_bounds__(512, 4)
void corr_kernel(const unsigned short* __restrict__ Qp, const unsigned short* __restrict__ Kp,
                 const unsigned short* __restrict__ Vt4, const float* __restrict__ src,
                 float* __restrict__ ws) {
  const int bid = blockIdx.x;
  const int b   = bid & 15;
  const int nt  = bid >> 4;          // 0..31, 64 n each
  const int tid = threadIdx.x;
  const int w   = tid >> 6;
  const int L   = tid & 63;
  const int lg  = L >> 4;
  const int ll  = L & 15;

  __shared__ __align__(16) char  stage[2*8*1280];     // 20 KB: double-buffered A' staging
  __shared__ __align__(16) float partial[8][64][4];   // 8 KB

  const unsigned short* Qb = Qp + (size_t)b*2048*32;
  const unsigned short* Kb = Kp + (size_t)b*2048*32;
  const unsigned short* Wb = Vt4 + (size_t)b*4*2048;

  const bf16x8 zero8 = {0,0,0,0,0,0,0,0};
  char* my0 = stage + w*1280;                 // buffer 0 (t2 even)
  char* my1 = stage + 8*1280 + w*1280;        // buffer 1 (t2 odd)
  char* wr00 = my0 + ll*80 + lg*8;  char* wr01 = wr00 + 32;
  char* wr10 = my1 + ll*80 + lg*8;  char* wr11 = wr10 + 32;
  const char* rd0 = my0 + ll*80 + lg*16;
  const char* rd1 = my1 + ll*80 + lg*16;

  // ---- Q-fragments for this block's 4 n-tiles ----
  bf16x8 bq1[4], bq2[4];
#pragma unroll
  for (int t2 = 0; t2 < 4; ++t2) {
    const unsigned short* qr = Qb + (size_t)(nt*64 + t2*16 + ll)*32;
    bq1[t2] = *(const bf16x8*)(qr + (lg & 1)*8);
    bf16x8 lo = *(const bf16x8*)(qr + 16 + (lg & 1)*8);
    bq2[t2] = (lg < 2) ? lo : zero8;
  }

  f32x4 accp[4];
#pragma unroll
  for (int t2 = 0; t2 < 4; ++t2) accp[t2] = (f32x4){0.f, 0.f, 0.f, 0.f};

  // compute step: QK MFMAs + exp2 + bf16 pack + stage into A' layout
#define STEP(T2, WRX0, WRX1)                                                   \
  do {                                                                         \
    f32x4 c0 = (f32x4){0.f,0.f,0.f,0.f};                                       \
    f32x4 c1 = (f32x4){0.f,0.f,0.f,0.f};                                       \
    c0 = __builtin_amdgcn_mfma_f32_16x16x32_bf16(a0, bq1[T2], c0, 0, 0, 0);    \
    c0 = __builtin_amdgcn_mfma_f32_16x16x32_bf16(a0, bq2[T2], c0, 0, 0, 0);    \
    c1 = __builtin_amdgcn_mfma_f32_16x16x32_bf16(a1, bq1[T2], c1, 0, 0, 0);    \
    c1 = __builtin_amdgcn_mfma_f32_16x16x32_bf16(a1, bq2[T2], c1, 0, 0, 0);    \
    float e0 = __builtin_amdgcn_exp2f(c0.x), e1v = __builtin_amdgcn_exp2f(c0.y);\
    float e2v = __builtin_amdgcn_exp2f(c0.z), e3 = __builtin_amdgcn_exp2f(c0.w);\
    float f0 = __builtin_amdgcn_exp2f(c1.x), f1 = __builtin_amdgcn_exp2f(c1.y);\
    float f2v = __builtin_amdgcn_exp2f(c1.z), f3 = __builtin_amdgcn_exp2f(c1.w);\
    *(uint2*)(WRX0) = make_uint2(f2bf(e0) | (f2bf(e1v) << 16),                 \
                                 f2bf(e2v) | (f2bf(e3) << 16));                \
    *(uint2*)(WRX1) = make_uint2(f2bf(f0) | (f2bf(f1) << 16),                  \
                                 f2bf(f2v) | (f2bf(f3) << 16));                \
  } while (0)

#define PV(T2P, RDX, WV)                                                       \
  do {                                                                         \
    bf16x8 pa = *(const bf16x8*)(RDX);                                         \
    accp[T2P] = __builtin_amdgcn_mfma_f32_16x16x32_bf16(pa, (WV), accp[T2P], 0, 0, 0); \
  } while (0)

  bool pend = false;
  bf16x8 wvp = zero8;
  for (int p = w; p < 64; p += 8) {
    const unsigned short* ar = Kb + (size_t)(p*32 + ll)*32;
    bf16x8 a0 = *(const bf16x8*)(ar + lg*8);            // m-tile 2p
    bf16x8 a1 = *(const bf16x8*)(ar + 16*32 + lg*8);    // m-tile 2p+1
    bf16x8 wv = zero8;                                  // W B-frag (cols>=4 zero)
    if (ll < 4) wv = *(const bf16x8*)(Wb + (size_t)ll*2048 + p*32 + lg*8);

    STEP(0, wr00, wr01);
    if (pend) PV(3, rd1, wvp);     // prev p's t2=3 (buffer 1)
    STEP(1, wr10, wr11);
    PV(0, rd0, wv);                // this p's t2=0 (buffer 0)
    STEP(2, wr00, wr01);
    PV(1, rd1, wv);                // this p's t2=1 (buffer 1)
    STEP(3, wr10, wr11);
    PV(2, rd0, wv);                // this p's t2=2 (buffer 0)
    wvp = wv; pend = true;
  }
  PV(3, rd1, wvp);                 // flush: last p's t2=3

#undef STEP
#undef PV

  // ---- write per-wave partials: X[j=ll][n] for ll<4 ----
  if (ll < 4) {
#pragma unroll
    for (int t2 = 0; t2 < 4; ++t2) {
      int nb = t2*16 + lg*4;
      partial[w][nb+0][ll] = accp[t2].x;
      partial[w][nb+1][ll] = accp[t2].y;
      partial[w][nb+2][ll] = accp[t2].z;
      partial[w][nb+3][ll] = accp[t2].w;
    }
  }
  __syncthreads();

  // ---- per-n finish + 15-value single-wave reduction (wave 0 only) ----
  if (tid < 64) {
    float4 s4 = make_float4(0.f, 0.f, 0.f, 0.f);
#pragma unroll
    for (int w2 = 0; w2 < 8; ++w2) {
      float4 pq = *(const float4*)&partial[w2][tid][0];
      s4.x += pq.x; s4.y += pq.y; s4.z += pq.z; s4.w += pq.w;
    }
    float inv = 1.0f / s4.x;
    float c0 = s4.y*inv, c1 = s4.z*inv, c2 = s4.w*inv;
    const int n = nt*64 + tid;
    const float* sp = src + (size_t)b*3*2048;
    float s0v = sp[n], s1v = sp[2048+n], s2v = sp[4096+n];
    float vals[15] = { c0, c1, c2, s0v, s1v, s2v,
                       s0v*c0, s0v*c1, s0v*c2,
                       s1v*c0, s1v*c1, s1v*c2,
                       s2v*c0, s2v*c1, s2v*c2 };
#pragma unroll
    for (int k = 0; k < 15; ++k) {
      float v = vals[k];
      v += __shfl_xor(v, 1);  v += __shfl_xor(v, 2);  v += __shfl_xor(v, 4);
      v += __shfl_xor(v, 8);  v += __shfl_xor(v, 16); v += __shfl_xor(v, 32);
      vals[k] = v;
    }
    if (tid == 0) {
#pragma unroll
      for (int k = 0; k < 15; ++k) ws[bid*16 + k] = vals[k];
    }
  }
}

// =============================================================================
// Kernel 2: 16 BLOCKS x 64 threads — one batch per block (round 12 layout).
// =============================================================================
__global__ __launch_bounds__(64)
void finalize_kernel(const float* __restrict__ ws, float* __restrict__ out) {
  const int b = blockIdx.x;
  const int L = threadIdx.x;

  float a = 0.0f;
  if (L < 15) {
#pragma unroll
    for (int ntile = 0; ntile < 32; ++ntile)
      a += ws[(ntile*16 + b)*16 + L];
  }
  float acc[15];
#pragma unroll
  for (int k = 0; k < 15; ++k) acc[k] = __shfl(a, k);

  if (L == 0) {
    const float invN = 1.0f/2048.0f;
    float Sc[3] = {acc[0], acc[1], acc[2]};
    float Ss[3] = {acc[3], acc[4], acc[5]};
    float cm[3] = {Sc[0]*invN, Sc[1]*invN, Sc[2]*invN};
    float sm[3] = {Ss[0]*invN, Ss[1]*invN, Ss[2]*invN};

    float A[3][3];
#pragma unroll
    for (int i = 0; i < 3; ++i)
#pragma unroll
      for (int j = 0; j < 3; ++j)
        A[i][j] = acc[6 + i*3 + j] - Ss[i]*cm[j];

    float u[3][3], vt[3][3];
    svd3_gesdd(A, u, vt);

    float R[3][3];
#pragma unroll
    for (int i = 0; i < 3; ++i)
#pragma unroll
      for (int k = 0; k < 3; ++k)
        R[i][k] = vt[i][0]*u[k][0] + vt[i][1]*u[k][1] + vt[i][2]*u[k][2];

    float det = R[0][0]*(R[1][1]*R[2][2] - R[1][2]*R[2][1])
              - R[0][1]*(R[1][0]*R[2][2] - R[1][2]*R[2][0])
              + R[0][2]*(R[1][0]*R[2][1] - R[1][1]*R[2][0]);

    if (det < 0.0f) {
#pragma unroll
      for (int i = 0; i < 3; ++i)
#pragma unroll
        for (int k = 0; k < 3; ++k)
          R[i][k] -= 2.0f*vt[i][2]*u[k][2];
    }

    float tv[3];
#pragma unroll
    for (int i = 0; i < 3; ++i)
      tv[i] = -(R[i][0]*sm[0] + R[i][1]*sm[1] + R[i][2]*sm[2]) + cm[i];

#pragma unroll
    for (int i = 0; i < 3; ++i)
#pragma unroll
      for (int j = 0; j < 3; ++j)
        out[b*9 + i*3 + j] = R[i][j];
#pragma unroll
    for (int i = 0; i < 3; ++i)
      out[144 + b*3 + i] = tv[i];
  }
}

extern "C" void kernel_launch(void* const* d_in, const int* in_sizes, int n_in,
                              void* d_out, int out_size, void* d_ws, size_t ws_size,
                              hipStream_t stream) {
  const float* srcE = (const float*)d_in[0];
  const float* tgtE = (const float*)d_in[1];
  const float* src  = (const float*)d_in[2];
  const float* tgt  = (const float*)d_in[3];
  float* out = (float*)d_out;

  // ws layout: [0,32KB) partials | Qp 2MB | Kp 2MB | Vt4 256KB
  float* part = (float*)d_ws;
  unsigned short* Qp  = (unsigned short*)((char*)d_ws + 32768);
  unsigned short* Kp  = (unsigned short*)((char*)d_ws + 32768 + (size_t)16*2048*32*2);
  unsigned short* Vt4 = (unsigned short*)((char*)d_ws + 32768 + (size_t)2*16*2048*32*2);

  hipLaunchKernelGGL(pack_kernel, dim3(256), dim3(128), 0, stream, srcE, tgtE, tgt, Qp, Kp, Vt4);
  hipLaunchKernelGGL(corr_kernel, dim3(512), dim3(512), 0, stream, Qp, Kp, Vt4, src, part);
  hipLaunchKernelGGL(finalize_kernel, dim3(16), dim3(64), 0, stream, part, out);
}

// Round 18
// 38.992 us; speedup vs baseline: 1.1937x; 1.0015x over previous
//
#include <hip/hip_runtime.h>
#include <math.h>

// LAPACK >= 3.10 slartg convention (c >= 0). Flip to 0 to emulate <= 3.9.
#define NEW_SLARTG 1

typedef __attribute__((ext_vector_type(8))) short bf16x8;
typedef __attribute__((ext_vector_type(4))) float f32x4;

// =============================================================================
// FINAL (round 18) = round-12 configuration, the measured optimum of this
// session (39.0 us; baseline 100.4 us).
// Session ledger (what mattered):
//   - MFMA flash attention w/ split-bf16 QK^T (f32-grade scores)   81.9 -> 40
//   - PV + softmax-sum via MFMA (P->bf16, LDS A'-relayout)          ~ -3
//   - 80B-stride staging (8-way bank conflict -> 2-way, free)        -3.4
//   - SVD fully scalarized (no runtime-indexed arrays -> no scratch) -5.4
//   - finalize one-SVD-per-CU (16 blocks; i-cache parallel fetch)    -8.4
// Falsified (all A/B-null or negative on this structure): L2 prefetch,
// occupancy 2x, VALU-poly exp, LDS RAW deferral, cooperative fusion,
// last-block atomic fusion. All pipes <25% busy at the 39 us floor.
// =============================================================================

__device__ __forceinline__ void slartg_f(float f, float g, float& c, float& s, float& r) {
#if NEW_SLARTG
  if (g == 0.0f) { c = 1.0f; s = 0.0f; r = f; }
  else if (f == 0.0f) { c = 0.0f; s = copysignf(1.0f, g); r = fabsf(g); }
  else {
    float d = sqrtf(f*f + g*g);
    c = fabsf(f) / d;
    r = copysignf(d, f);
    s = g / r;
  }
#else
  if (g == 0.0f) { c = 1.0f; s = 0.0f; r = f; }
  else if (f == 0.0f) { c = 0.0f; s = 1.0f; r = g; }
  else {
    float d = sqrtf(f*f + g*g);
    c = f / d; s = g / d; r = d;
    if (fabsf(f) > fabsf(g) && c < 0.0f) { c = -c; s = -s; r = -r; }
  }
#endif
}

__device__ __forceinline__ void slas2_f(float f, float g, float h, float& ssmin, float& ssmax) {
  float fa = fabsf(f), ga = fabsf(g), ha = fabsf(h);
  float fhmn = fminf(fa, ha), fhmx = fmaxf(fa, ha);
  if (fhmn == 0.0f) {
    ssmin = 0.0f;
    if (fhmx == 0.0f) ssmax = ga;
    else {
      float mn = fminf(fhmx, ga), mx = fmaxf(fhmx, ga);
      float qq = mn / mx;
      ssmax = mx * sqrtf(1.0f + qq*qq);
    }
  } else {
    if (ga < fhmx) {
      float as_ = 1.0f + fhmn/fhmx;
      float at_ = (fhmx - fhmn)/fhmx;
      float au_ = ga/fhmx; au_ = au_*au_;
      float c = 2.0f/(sqrtf(as_*as_ + au_) + sqrtf(at_*at_ + au_));
      ssmin = fhmn*c;
      ssmax = fhmx/c;
    } else {
      float au_ = fhmx/ga;
      if (au_ == 0.0f) {
        ssmin = (fhmn*fhmx)/ga;
        ssmax = ga;
      } else {
        float as_ = 1.0f + fhmn/fhmx;
        float at_ = (fhmx - fhmn)/fhmx;
        float t1 = as_*au_, t2 = at_*au_;
        float c = 1.0f/(sqrtf(1.0f + t1*t1) + sqrtf(1.0f + t2*t2));
        ssmin = (fhmn*c)*au_;
        ssmin = ssmin + ssmin;
        ssmax = ga/(c + c);
      }
    }
  }
}

__device__ __forceinline__ void slasv2_f(float f, float g, float h,
                         float& ssmin, float& ssmax,
                         float& snr, float& csr, float& snl, float& csl) {
  const float eps = 5.9604645e-08f;
  float ft = f, fa = fabsf(f), ht = h, ha = fabsf(h);
  int pmax = 1;
  bool swap_ = (ha > fa);
  if (swap_) {
    pmax = 3;
    float tq = ft; ft = ht; ht = tq;
    tq = fa; fa = ha; ha = tq;
  }
  float gt = g, ga = fabsf(g);
  float clt = 0.f, crt = 0.f, slt = 0.f, srt = 0.f;
  if (ga == 0.0f) {
    ssmin = ha; ssmax = fa;
    clt = 1.0f; crt = 1.0f; slt = 0.0f; srt = 0.0f;
  } else {
    bool gasmal = true;
    if (ga > fa) {
      pmax = 2;
      if ((fa/ga) < eps) {
        gasmal = false;
        ssmax = ga;
        ssmin = (ha > 1.0f) ? (fa/(ga/ha)) : ((fa/ga)*ha);
        clt = 1.0f; slt = ht/gt; srt = 1.0f; crt = ft/gt;
      }
    }
    if (gasmal) {
      float dd = fa - ha;
      float l = (dd == fa) ? 1.0f : (dd/fa);
      float mr = gt/ft;
      float t = 2.0f - l;
      float mm2 = mr*mr, tt = t*t;
      float s_ = sqrtf(tt + mm2);
      float r_ = (l == 0.0f) ? fabsf(mr) : sqrtf(l*l + mm2);
      float a_ = 0.5f*(s_ + r_);
      ssmin = ha/a_;
      ssmax = fa*a_;
      if (mm2 == 0.0f) {
        if (l == 0.0f) t = copysignf(2.0f, ft)*copysignf(1.0f, gt);
        else t = gt/copysignf(dd, ft) + mr/t;
      } else {
        t = (mr/(s_ + t) + mr/(r_ + l))*(1.0f + a_);
      }
      float l2 = sqrtf(t*t + 4.0f);
      crt = 2.0f/l2;
      srt = t/l2;
      clt = (crt + srt*mr)/a_;
      slt = (ht/ft)*srt/a_;
    }
  }
  if (swap_) { csl = srt; snl = crt; csr = slt; snr = clt; }
  else       { csl = clt; snl = slt; csr = crt; snr = srt; }
  float tsign = 0.f;
  if (pmax == 1) tsign = copysignf(1.0f, csr)*copysignf(1.0f, csl)*copysignf(1.0f, f);
  if (pmax == 2) tsign = copysignf(1.0f, snr)*copysignf(1.0f, csl)*copysignf(1.0f, g);
  if (pmax == 3) tsign = copysignf(1.0f, snr)*copysignf(1.0f, snl)*copysignf(1.0f, h);
  ssmax = copysignf(ssmax, tsign);
  ssmin = copysignf(ssmin, tsign*copysignf(1.0f, f)*copysignf(1.0f, h));
}

// rotation / swap helpers with COMPILE-TIME indices (template params)
template<int R1, int R2>
__device__ __forceinline__ void rotr(float mt[3][3], float c, float s) {
#pragma unroll
  for (int k = 0; k < 3; ++k) {
    float x = mt[R1][k], y = mt[R2][k];
    mt[R1][k] = c*x + s*y;
    mt[R2][k] = c*y - s*x;
  }
}
template<int C1, int C2>
__device__ __forceinline__ void rotc(float mt[3][3], float c, float s) {
#pragma unroll
  for (int k = 0; k < 3; ++k) {
    float x = mt[k][C1], y = mt[k][C2];
    mt[k][C1] = c*x + s*y;
    mt[k][C2] = c*y - s*x;
  }
}
template<int R1, int R2>
__device__ __forceinline__ void swaprow(float mt[3][3]) {
#pragma unroll
  for (int k = 0; k < 3; ++k) { float t = mt[R1][k]; mt[R1][k] = mt[R2][k]; mt[R2][k] = t; }
}
template<int C1, int C2>
__device__ __forceinline__ void swapcol(float mt[3][3]) {
#pragma unroll
  for (int k = 0; k < 3; ++k) { float t = mt[k][C1]; mt[k][C1] = mt[k][C2]; mt[k][C2] = t; }
}

// SBDSQR specialized for n=3 upper bidiagonal, all-register state.
__device__ __forceinline__ void sbdsqr3_reg(float& d1, float& d2, float& d3,
                                            float& e1, float& e2,
                                            float u[3][3], float vt[3][3]) {
  const float eps  = 5.9604645e-08f;
  const float unfl = 1.17549435e-38f;
  const float tol  = 10.0f*eps;

  float sminoa = fabsf(d1);
  if (sminoa != 0.0f) {
    float mu = sminoa;
    mu = fabsf(d2)*(mu/(mu + fabsf(e1)));
    sminoa = fminf(sminoa, mu);
    if (sminoa != 0.0f) {
      mu = fabsf(d3)*(mu/(mu + fabsf(e2)));
      sminoa = fminf(sminoa, mu);
    }
  }
  sminoa = sminoa / sqrtf(3.0f);
  float thresh = fmaxf(tol*sminoa, 54.0f*unfl);

  int m = 3, oldll = -1, oldm = -1, idir = 0;
  int guard = 0;
  while (m > 1 && ++guard < 200) {
    if (m == 2) {
      if (fabsf(e1) <= thresh) { e1 = 0.0f; m = 1; continue; }
      float sigmn, sigmx, sinr, cosr, sinl, cosl;
      slasv2_f(d1, e1, d2, sigmn, sigmx, sinr, cosr, sinl, cosl);
      d1 = sigmx; d2 = sigmn; e1 = 0.0f;
      rotr<0,1>(vt, cosr, sinr);
      rotc<0,1>(u,  cosl, sinl);
      m = 0; continue;
    }
    // ---- m == 3 ----
    float smax = fabsf(d3);
    if (fabsf(e2) <= thresh) { e2 = 0.0f; m = 2; continue; }
    smax = fmaxf(smax, fmaxf(fabsf(d2), fabsf(e2)));
    if (fabsf(e1) <= thresh) {
      e1 = 0.0f;
      float sigmn, sigmx, sinr, cosr, sinl, cosl;
      slasv2_f(d2, e2, d3, sigmn, sigmx, sinr, cosr, sinl, cosl);
      d2 = sigmx; d3 = sigmn; e2 = 0.0f;
      rotr<1,2>(vt, cosr, sinr);
      rotc<1,2>(u,  cosl, sinl);
      m = 1; continue;
    }
    smax = fmaxf(smax, fmaxf(fabsf(d1), fabsf(e1)));

    if (1 > oldm || 3 < oldll)
      idir = (fabsf(d1) >= fabsf(d3)) ? 1 : 2;

    float sminl = 0.0f;
    if (idir == 1) {
      if (fabsf(e2) <= tol*fabsf(d3)) { e2 = 0.0f; continue; }
      float mu = fabsf(d1); sminl = mu;
      if (fabsf(e1) <= tol*mu) { e1 = 0.0f; continue; }
      mu = fabsf(d2)*(mu/(mu + fabsf(e1))); sminl = fminf(sminl, mu);
      if (fabsf(e2) <= tol*mu) { e2 = 0.0f; continue; }
      mu = fabsf(d3)*(mu/(mu + fabsf(e2))); sminl = fminf(sminl, mu);
    } else {
      if (fabsf(e1) <= tol*fabsf(d1)) { e1 = 0.0f; continue; }
      float mu = fabsf(d3); sminl = mu;
      if (fabsf(e2) <= tol*mu) { e2 = 0.0f; continue; }
      mu = fabsf(d2)*(mu/(mu + fabsf(e2))); sminl = fminf(sminl, mu);
      if (fabsf(e1) <= tol*mu) { e1 = 0.0f; continue; }
      mu = fabsf(d1)*(mu/(mu + fabsf(e1))); sminl = fminf(sminl, mu);
    }
    oldll = 1; oldm = 3;

    float shift = 0.0f, rdum;
    if (!(3.0f*tol*(sminl/smax) <= fmaxf(eps, 0.01f*tol))) {
      float sll;
      if (idir == 1) { sll = fabsf(d1); slas2_f(d2, e2, d3, shift, rdum); }
      else           { sll = fabsf(d3); slas2_f(d1, e1, d2, shift, rdum); }
      if (sll > 0.0f) { float qq = shift/sll; if (qq*qq < eps) shift = 0.0f; }
    }

    if (shift == 0.0f) {
      if (idir == 1) {
        float cs = 1.0f, oldcs = 1.0f, sn = 0.0f, oldsn = 0.0f, r;
        float c10, s10, c20, s20, c11, s11, c21, s21;
        slartg_f(d1*cs, e1, cs, sn, r);
        slartg_f(oldcs*r, d2*sn, oldcs, oldsn, d1);
        c10 = cs; s10 = sn; c20 = oldcs; s20 = oldsn;
        slartg_f(d2*cs, e2, cs, sn, r);
        e1 = oldsn*r;
        slartg_f(oldcs*r, d3*sn, oldcs, oldsn, d2);
        c11 = cs; s11 = sn; c21 = oldcs; s21 = oldsn;
        float h = d3*cs;
        d3 = h*oldcs; e2 = h*oldsn;
        rotr<0,1>(vt, c10, s10); rotr<1,2>(vt, c11, s11);
        rotc<0,1>(u,  c20, s20); rotc<1,2>(u,  c21, s21);
        if (fabsf(e2) <= thresh) e2 = 0.0f;
      } else {
        float cs = 1.0f, oldcs = 1.0f, sn = 0.0f, oldsn = 0.0f, r;
        float c10, s10, c20, s20, c11, s11, c21, s21;
        slartg_f(d3*cs, e2, cs, sn, r);
        slartg_f(oldcs*r, d2*sn, oldcs, oldsn, d3);
        c11 = cs; s11 = -sn; c21 = oldcs; s21 = -oldsn;
        slartg_f(d2*cs, e1, cs, sn, r);
        e2 = oldsn*r;
        slartg_f(oldcs*r, d1*sn, oldcs, oldsn, d2);
        c10 = cs; s10 = -sn; c20 = oldcs; s20 = -oldsn;
        float h = d1*cs;
        d1 = h*oldcs; e1 = h*oldsn;
        rotr<1,2>(vt, c21, s21); rotr<0,1>(vt, c20, s20);
        rotc<1,2>(u,  c11, s11); rotc<0,1>(u,  c10, s10);
        if (fabsf(e1) <= thresh) e1 = 0.0f;
      }
    } else {
      if (idir == 1) {
        float f = (fabsf(d1) - shift)*(copysignf(1.0f, d1) + shift/d1);
        float g = e1, cr, sr, cl, sl, r;
        float c10, s10, c20, s20, c11, s11, c21, s21;
        slartg_f(f, g, cr, sr, r);
        f = cr*d1 + sr*e1;  e1 = cr*e1 - sr*d1;
        g = sr*d2;  d2 = cr*d2;
        slartg_f(f, g, cl, sl, r);
        d1 = r;  f = cl*e1 + sl*d2;  d2 = cl*d2 - sl*e1;
        g = sl*e2;  e2 = cl*e2;
        c10 = cr; s10 = sr; c20 = cl; s20 = sl;
        slartg_f(f, g, cr, sr, r);
        e1 = r;
        f = cr*d2 + sr*e2;  e2 = cr*e2 - sr*d2;
        g = sr*d3;  d3 = cr*d3;
        slartg_f(f, g, cl, sl, r);
        d2 = r;  f = cl*e2 + sl*d3;  d3 = cl*d3 - sl*e2;
        c11 = cr; s11 = sr; c21 = cl; s21 = sl;
        e2 = f;
        rotr<0,1>(vt, c10, s10); rotr<1,2>(vt, c11, s11);
        rotc<0,1>(u,  c20, s20); rotc<1,2>(u,  c21, s21);
        if (fabsf(e2) <= thresh) e2 = 0.0f;
      } else {
        float f = (fabsf(d3) - shift)*(copysignf(1.0f, d3) + shift/d3);
        float g = e2, cr, sr, cl, sl, r;
        float c10, s10, c20, s20, c11, s11, c21, s21;
        slartg_f(f, g, cr, sr, r);
        f = cr*d3 + sr*e2;  e2 = cr*e2 - sr*d3;
        g = sr*d2;  d2 = cr*d2;
        slartg_f(f, g, cl, sl, r);
        d3 = r;  f = cl*e2 + sl*d2;  d2 = cl*d2 - sl*e2;
        g = sl*e1;  e1 = cl*e1;
        c11 = cr; s11 = -sr; c21 = cl; s21 = -sl;
        slartg_f(f, g, cr, sr, r);
        e2 = r;
        f = cr*d2 + sr*e1;  e1 = cr*e1 - sr*d2;
        g = sr*d1;  d1 = cr*d1;
        slartg_f(f, g, cl, sl, r);
        d2 = r;  f = cl*e1 + sl*d1;  d1 = cl*d1 - sl*e1;
        c10 = cr; s10 = -sr; c20 = cl; s20 = -sl;
        e1 = f;
        if (fabsf(e1) <= thresh) e1 = 0.0f;
        rotr<1,2>(vt, c21, s21); rotr<0,1>(vt, c20, s20);
        rotc<1,2>(u,  c11, s11); rotc<0,1>(u,  c10, s10);
      }
    }
  }

  if (d1 < 0.0f) { d1 = -d1; vt[0][0] = -vt[0][0]; vt[0][1] = -vt[0][1]; vt[0][2] = -vt[0][2]; }
  if (d2 < 0.0f) { d2 = -d2; vt[1][0] = -vt[1][0]; vt[1][1] = -vt[1][1]; vt[1][2] = -vt[1][2]; }
  if (d3 < 0.0f) { d3 = -d3; vt[2][0] = -vt[2][0]; vt[2][1] = -vt[2][1]; vt[2][2] = -vt[2][2]; }

  { // pass 1: min of (d1,d2,d3) -> slot 3
    int isub = 1; float smn = d1;
    if (d2 <= smn) { isub = 2; smn = d2; }
    if (d3 <= smn) { isub = 3; smn = d3; }
    if (isub == 1)      { d1 = d3; d3 = smn; swaprow<0,2>(vt); swapcol<0,2>(u); }
    else if (isub == 2) { d2 = d3; d3 = smn; swaprow<1,2>(vt); swapcol<1,2>(u); }
  }
  { // pass 2: min of (d1,d2) -> slot 2
    int isub = 1; float smn = d1;
    if (d2 <= smn) { isub = 2; smn = d2; }
    if (isub == 1) { d1 = d2; d2 = smn; swaprow<0,1>(vt); swapcol<0,1>(u); }
  }
}

__device__ __forceinline__ void svd3_gesdd(const float Ain[3][3], float u[3][3], float vt[3][3]) {
  float a[3][3];
#pragma unroll
  for (int i = 0; i < 3; ++i)
#pragma unroll
    for (int j = 0; j < 3; ++j) a[i][j] = Ain[i][j];

  float d1, d2, d3, e1, e2;
  float tq0 = 0.f, tq1 = 0.f, tp0 = 0.f;
  float v0a = 0.f, v0b = 0.f, v1a = 0.f, p0a = 0.f;

  {
    float alpha = a[0][0];
    float xn = sqrtf(a[1][0]*a[1][0] + a[2][0]*a[2][0]);
    if (xn == 0.0f) { tq0 = 0.0f; d1 = alpha; }
    else {
      float beta = -copysignf(sqrtf(alpha*alpha + xn*xn), alpha);
      tq0 = (beta - alpha)/beta;
      float sc = 1.0f/(alpha - beta);
      v0a = a[1][0]*sc; v0b = a[2][0]*sc;
      d1 = beta;
    }
#pragma unroll
    for (int j = 1; j < 3; ++j) {
      float w = (a[0][j] + v0a*a[1][j] + v0b*a[2][j])*tq0;
      a[0][j] -= w; a[1][j] -= w*v0a; a[2][j] -= w*v0b;
    }
  }
  {
    float alpha = a[0][1];
    float xn = fabsf(a[0][2]);
    if (xn == 0.0f) { tp0 = 0.0f; e1 = alpha; }
    else {
      float beta = -copysignf(sqrtf(alpha*alpha + xn*xn), alpha);
      tp0 = (beta - alpha)/beta;
      p0a = a[0][2]/(alpha - beta);
      e1 = beta;
    }
#pragma unroll
    for (int i = 1; i < 3; ++i) {
      float w = (a[i][1] + p0a*a[i][2])*tp0;
      a[i][1] -= w; a[i][2] -= w*p0a;
    }
  }
  {
    float alpha = a[1][1];
    float xn = fabsf(a[2][1]);
    if (xn == 0.0f) { tq1 = 0.0f; d2 = alpha; }
    else {
      float beta = -copysignf(sqrtf(alpha*alpha + xn*xn), alpha);
      tq1 = (beta - alpha)/beta;
      v1a = a[2][1]/(alpha - beta);
      d2 = beta;
    }
    float w = (a[1][2] + v1a*a[2][2])*tq1;
    a[1][2] -= w; a[2][2] -= w*v1a;
  }
  e2 = a[1][2];
  d3 = a[2][2];

  float ub[3][3] = {{1,0,0},{0,1,0},{0,0,1}};
  float vb[3][3] = {{1,0,0},{0,1,0},{0,0,1}};
  sbdsqr3_reg(d1, d2, d3, e1, e2, ub, vb);

#pragma unroll
  for (int j = 0; j < 3; ++j) {
    float w = (ub[1][j] + v1a*ub[2][j])*tq1;
    ub[1][j] -= w; ub[2][j] -= w*v1a;
  }
#pragma unroll
  for (int j = 0; j < 3; ++j) {
    float w = (ub[0][j] + v0a*ub[1][j] + v0b*ub[2][j])*tq0;
    ub[0][j] -= w; ub[1][j] -= w*v0a; ub[2][j] -= w*v0b;
  }
#pragma unroll
  for (int i = 0; i < 3; ++i) {
    float w = (vb[i][1] + p0a*vb[i][2])*tp0;
    vb[i][1] -= w; vb[i][2] -= w*p0a;
  }
#pragma unroll
  for (int i = 0; i < 3; ++i)
#pragma unroll
    for (int j = 0; j < 3; ++j) { u[i][j] = ub[i][j]; vt[i][j] = vb[i][j]; }
}

// =============================================================================
// bf16 helpers (RNE, manual — verified since round 1)
// =============================================================================
__device__ __forceinline__ unsigned int f2bf(float x) {
  unsigned int u = __float_as_uint(x);
  return (u + 0x7FFFu + ((u >> 16) & 1u)) >> 16;
}
__device__ __forceinline__ float bf2f(unsigned int h) {
  return __uint_as_float(h << 16);
}

// =============================================================================
// Kernel 0: pack.
//   Qp row (64B): [qh(16)|ql(16)]  (pre-scaled by 0.25*log2e)
//   Kp row (64B): [kh(16)|kl(16)]
//   W table (bf16): Vt4[b][4][2048]: row 0 = 1.0, rows 1..3 = tgt components.
// =============================================================================
__global__ __launch_bounds__(128)
void pack_kernel(const float* __restrict__ srcE, const float* __restrict__ tgtE,
                 const float* __restrict__ tgt,
                 unsigned short* __restrict__ Qp, unsigned short* __restrict__ Kp,
                 unsigned short* __restrict__ Vt4) {
  const int g = blockIdx.x*128 + threadIdx.x;   // 32768 = 16*2048
  const int b = g >> 11, n = g & 2047;
  const float* qs = srcE + (size_t)b*16*2048 + n;
  const float* ks = tgtE + (size_t)b*16*2048 + n;
  const float QSCALE = 0.25f * 1.44269504088896340736f;

  unsigned short qrow[32], krow[32];
#pragma unroll
  for (int dd = 0; dd < 16; ++dd) {
    float q = qs[dd*2048] * QSCALE;
    unsigned int qh = f2bf(q);
    qrow[dd] = (unsigned short)qh; qrow[16+dd] = (unsigned short)f2bf(q - bf2f(qh));
    float k = ks[dd*2048];
    unsigned int kh = f2bf(k);
    krow[dd] = (unsigned short)kh; krow[16+dd] = (unsigned short)f2bf(k - bf2f(kh));
  }
  uint4* qdst = (uint4*)(Qp + (size_t)g*32);
  uint4* kdst = (uint4*)(Kp + (size_t)g*32);
#pragma unroll
  for (int i = 0; i < 4; ++i) { qdst[i] = ((uint4*)qrow)[i]; kdst[i] = ((uint4*)krow)[i]; }

  const float* vp = tgt + (size_t)b*3*2048 + n;
  unsigned short* wb = Vt4 + (size_t)b*4*2048;
  wb[n]          = 0x3F80;             // ones column (j=0)
  wb[2048 + n]   = (unsigned short)f2bf(vp[0]);
  wb[2*2048 + n] = (unsigned short)f2bf(vp[2048]);
  wb[3*2048 + n] = (unsigned short)f2bf(vp[4096]);
}

// =============================================================================
// Kernel 1: MFMA flash attention; PV + softmax-sum via MFMA.
// grid = 512: bid = nt*16 + b. block = 512 (8 waves), 64 n per block.
// Per (p,t2): 4 QK MFMAs (split-bf16) -> 8 hw exp2 -> f2bf pack -> A'-staging
// in LDS (80B rows, conflict-free) -> 1 PV MFMA vs W=[1|v0|v1|v2].
// =============================================================================
__global__ __launch_bounds__(512, 4)
void corr_kernel(const unsigned short* __restrict__ Qp, const unsigned short* __restrict__ Kp,
                 const unsigned short* __restrict__ Vt4, const float* __restrict__ src,
                 float* __restrict__ ws) {
  const int bid = blockIdx.x;
  const int b   = bid & 15;
  const int nt  = bid >> 4;          // 0..31, 64 n each
  const int tid = threadIdx.x;
  const int w   = tid >> 6;
  const int L   = tid & 63;
  const int lg  = L >> 4;
  const int ll  = L & 15;

  __shared__ __align__(16) char  stage[8*1280];       // 10 KB: per-wave A' staging (80B rows)
  __shared__ __align__(16) float partial[8][64][4];   // 8 KB

  const unsigned short* Qb = Qp + (size_t)b*2048*32;
  const unsigned short* Kb = Kp + (size_t)b*2048*32;
  const unsigned short* Wb = Vt4 + (size_t)b*4*2048;

  const bf16x8 zero8 = {0,0,0,0,0,0,0,0};
  char* my = stage + w*1280;
  char* wr0 = my + ll*80 + lg*8;        // tile0 write slot
  char* wr1 = wr0 + 32;                 // tile1 write slot
  const char* rd = my + ll*80 + lg*16;  // A'-frag read slot (16B aligned: 80=16*5)

  // ---- Q-fragments for this block's 4 n-tiles ----
  bf16x8 bq1[4], bq2[4];
#pragma unroll
  for (int t2 = 0; t2 < 4; ++t2) {
    const unsigned short* qr = Qb + (size_t)(nt*64 + t2*16 + ll)*32;
    bq1[t2] = *(const bf16x8*)(qr + (lg & 1)*8);
    bf16x8 lo = *(const bf16x8*)(qr + 16 + (lg & 1)*8);
    bq2[t2] = (lg < 2) ? lo : zero8;
  }

  f32x4 accp[4];
#pragma unroll
  for (int t2 = 0; t2 < 4; ++t2) accp[t2] = (f32x4){0.f, 0.f, 0.f, 0.f};

  for (int p = w; p < 64; p += 8) {
    const unsigned short* ar = Kb + (size_t)(p*32 + ll)*32;
    bf16x8 a0 = *(const bf16x8*)(ar + lg*8);            // m-tile 2p
    bf16x8 a1 = *(const bf16x8*)(ar + 16*32 + lg*8);    // m-tile 2p+1
    bf16x8 wv = zero8;                                  // W B-frag (cols>=4 zero)
    if (ll < 4) wv = *(const bf16x8*)(Wb + (size_t)ll*2048 + p*32 + lg*8);

#pragma unroll
    for (int t2 = 0; t2 < 4; ++t2) {
      f32x4 c0 = (f32x4){0.f,0.f,0.f,0.f};
      f32x4 c1 = (f32x4){0.f,0.f,0.f,0.f};
      c0 = __builtin_amdgcn_mfma_f32_16x16x32_bf16(a0, bq1[t2], c0, 0, 0, 0);
      c0 = __builtin_amdgcn_mfma_f32_16x16x32_bf16(a0, bq2[t2], c0, 0, 0, 0);
      c1 = __builtin_amdgcn_mfma_f32_16x16x32_bf16(a1, bq1[t2], c1, 0, 0, 0);
      c1 = __builtin_amdgcn_mfma_f32_16x16x32_bf16(a1, bq2[t2], c1, 0, 0, 0);
      // P = exp2(scores); C-frag: row m_loc = lg*4+r, col n = ll
      float e0 = __builtin_amdgcn_exp2f(c0.x), e1 = __builtin_amdgcn_exp2f(c0.y);
      float e2 = __builtin_amdgcn_exp2f(c0.z), e3 = __builtin_amdgcn_exp2f(c0.w);
      float f0 = __builtin_amdgcn_exp2f(c1.x), f1 = __builtin_amdgcn_exp2f(c1.y);
      float f2 = __builtin_amdgcn_exp2f(c1.z), f3 = __builtin_amdgcn_exp2f(c1.w);
      // pack to bf16 pairs (lo = even r) and stage into A' layout
      *(uint2*)wr0 = make_uint2(f2bf(e0) | (f2bf(e1) << 16),
                                f2bf(e2) | (f2bf(e3) << 16));
      *(uint2*)wr1 = make_uint2(f2bf(f0) | (f2bf(f1) << 16),
                                f2bf(f2) | (f2bf(f3) << 16));
      bf16x8 pa = *(const bf16x8*)rd;   // A'[row=ll][k=lg*8..+7]
      // PV: X[n][j] += P^T x W   (j: 0=sumE, 1..3 = sum e*v)
      accp[t2] = __builtin_amdgcn_mfma_f32_16x16x32_bf16(pa, wv, accp[t2], 0, 0, 0);
    }
  }

  // ---- write per-wave partials: X[j=ll][n] for ll<4 ----
  if (ll < 4) {
#pragma unroll
    for (int t2 = 0; t2 < 4; ++t2) {
      int nb = t2*16 + lg*4;
      partial[w][nb+0][ll] = accp[t2].x;
      partial[w][nb+1][ll] = accp[t2].y;
      partial[w][nb+2][ll] = accp[t2].z;
      partial[w][nb+3][ll] = accp[t2].w;
    }
  }
  __syncthreads();

  // ---- per-n finish + 15-value single-wave reduction (wave 0 only) ----
  if (tid < 64) {
    float4 s4 = make_float4(0.f, 0.f, 0.f, 0.f);
#pragma unroll
    for (int w2 = 0; w2 < 8; ++w2) {
      float4 pq = *(const float4*)&partial[w2][tid][0];
      s4.x += pq.x; s4.y += pq.y; s4.z += pq.z; s4.w += pq.w;
    }
    float inv = 1.0f / s4.x;
    float c0 = s4.y*inv, c1 = s4.z*inv, c2 = s4.w*inv;
    const int n = nt*64 + tid;
    const float* sp = src + (size_t)b*3*2048;
    float s0v = sp[n], s1v = sp[2048+n], s2v = sp[4096+n];
    float vals[15] = { c0, c1, c2, s0v, s1v, s2v,
                       s0v*c0, s0v*c1, s0v*c2,
                       s1v*c0, s1v*c1, s1v*c2,
                       s2v*c0, s2v*c1, s2v*c2 };
#pragma unroll
    for (int k = 0; k < 15; ++k) {
      float v = vals[k];
      v += __shfl_xor(v, 1);  v += __shfl_xor(v, 2);  v += __shfl_xor(v, 4);
      v += __shfl_xor(v, 8);  v += __shfl_xor(v, 16); v += __shfl_xor(v, 32);
      vals[k] = v;
    }
    if (tid == 0) {
#pragma unroll
      for (int k = 0; k < 15; ++k) ws[bid*16 + k] = vals[k];
    }
  }
}

// =============================================================================
// Kernel 2: 16 BLOCKS x 64 threads — one batch per block, one CU each
// (parallel i-fetch; register-resident LAPACK-faithful SVD on lane 0).
// =============================================================================
__global__ __launch_bounds__(64)
void finalize_kernel(const float* __restrict__ ws, float* __restrict__ out) {
  const int b = blockIdx.x;
  const int L = threadIdx.x;

  float a = 0.0f;
  if (L < 15) {
#pragma unroll
    for (int ntile = 0; ntile < 32; ++ntile)
      a += ws[(ntile*16 + b)*16 + L];
  }
  float acc[15];
#pragma unroll
  for (int k = 0; k < 15; ++k) acc[k] = __shfl(a, k);

  if (L == 0) {
    const float invN = 1.0f/2048.0f;
    float Sc[3] = {acc[0], acc[1], acc[2]};
    float Ss[3] = {acc[3], acc[4], acc[5]};
    float cm[3] = {Sc[0]*invN, Sc[1]*invN, Sc[2]*invN};
    float sm[3] = {Ss[0]*invN, Ss[1]*invN, Ss[2]*invN};

    float A[3][3];
#pragma unroll
    for (int i = 0; i < 3; ++i)
#pragma unroll
      for (int j = 0; j < 3; ++j)
        A[i][j] = acc[6 + i*3 + j] - Ss[i]*cm[j];

    float u[3][3], vt[3][3];
    svd3_gesdd(A, u, vt);

    float R[3][3];
#pragma unroll
    for (int i = 0; i < 3; ++i)
#pragma unroll
      for (int k = 0; k < 3; ++k)
        R[i][k] = vt[i][0]*u[k][0] + vt[i][1]*u[k][1] + vt[i][2]*u[k][2];

    float det = R[0][0]*(R[1][1]*R[2][2] - R[1][2]*R[2][1])
              - R[0][1]*(R[1][0]*R[2][2] - R[1][2]*R[2][0])
              + R[0][2]*(R[1][0]*R[2][1] - R[1][1]*R[2][0]);

    if (det < 0.0f) {
#pragma unroll
      for (int i = 0; i < 3; ++i)
#pragma unroll
        for (int k = 0; k < 3; ++k)
          R[i][k] -= 2.0f*vt[i][2]*u[k][2];
    }

    float tv[3];
#pragma unroll
    for (int i = 0; i < 3; ++i)
      tv[i] = -(R[i][0]*sm[0] + R[i][1]*sm[1] + R[i][2]*sm[2]) + cm[i];

#pragma unroll
    for (int i = 0; i < 3; ++i)
#pragma unroll
      for (int j = 0; j < 3; ++j)
        out[b*9 + i*3 + j] = R[i][j];
#pragma unroll
    for (int i = 0; i < 3; ++i)
      out[144 + b*3 + i] = tv[i];
  }
}

extern "C" void kernel_launch(void* const* d_in, const int* in_sizes, int n_in,
                              void* d_out, int out_size, void* d_ws, size_t ws_size,
                              hipStream_t stream) {
  const float* srcE = (const float*)d_in[0];
  const float* tgtE = (const float*)d_in[1];
  const float* src  = (const float*)d_in[2];
  const float* tgt  = (const float*)d_in[3];
  float* out = (float*)d_out;

  // ws layout: [0,32KB) partials | Qp 2MB | Kp 2MB | Vt4 256KB
  float* part = (float*)d_ws;
  unsigned short* Qp  = (unsigned short*)((char*)d_ws + 32768);
  unsigned short* Kp  = (unsigned short*)((char*)d_ws + 32768 + (size_t)16*2048*32*2);
  unsigned short* Vt4 = (unsigned short*)((char*)d_ws + 32768 + (size_t)2*16*2048*32*2);

  hipLaunchKernelGGL(pack_kernel, dim3(256), dim3(128), 0, stream, srcE, tgtE, tgt, Qp, Kp, Vt4);
  hipLaunchKernelGGL(corr_kernel, dim3(512), dim3(512), 0, stream, Qp, Kp, Vt4, src, part);
  hipLaunchKernelGGL(finalize_kernel, dim3(16), dim3(64), 0, stream, part, out);
}